// Round 1
// baseline (2365.162 us; speedup 1.0000x reference)
//
#include <hip/hip_runtime.h>
#include <math.h>

#define D_   256
#define H_   8
#define L_   2
#define FF_  1024
#define S_   512
#define B_   32
#define M_   4096
#define NC_  10
#define ROWS (B_*S_)   // 16384

__device__ __forceinline__ float wave_sum(float v) {
#pragma unroll
  for (int off = 1; off < 64; off <<= 1) v += __shfl_xor(v, off, 64);
  return v;
}

// ---------------- embedding ----------------
__global__ __launch_bounds__(256) void emb_kernel(const int* __restrict__ ids,
                                                  const float* __restrict__ tok,
                                                  const float* __restrict__ pos,
                                                  float* __restrict__ x) {
  const int row  = blockIdx.x * 4 + (threadIdx.x >> 6);
  const int lane = threadIdx.x & 63;
  const int id = ids[row];
  const int s  = row & (S_ - 1);
  const float4 t = *(const float4*)(tok + (size_t)id * D_ + lane * 4);
  const float4 p = *(const float4*)(pos + (size_t)s  * D_ + lane * 4);
  float4 r; r.x = t.x + p.x; r.y = t.y + p.y; r.z = t.z + p.z; r.w = t.w + p.w;
  *(float4*)(x + (size_t)row * D_ + lane * 4) = r;
}

// ---------------- generic GEMM: C[M,N] = A[M,K] * B[N,K]^T + bias (+ReLU) ----
template<int RELU>
__global__ __launch_bounds__(256) void gemm_bt(const float* __restrict__ A,
                                               const float* __restrict__ Bm,
                                               const float* __restrict__ bias,
                                               float* __restrict__ C,
                                               int M, int N, int K) {
  __shared__ float As[16][68];
  __shared__ float Bs[16][68];
  const int tid = threadIdx.x;
  const int tx = tid & 15, ty = tid >> 4;
  const int m0 = blockIdx.y * 64, n0 = blockIdx.x * 64;
  const int lr = tid >> 2;            // 0..63 row within tile
  const int lc = (tid & 3) << 2;      // 0,4,8,12 k offset
  const float* Aptr = A + (size_t)(m0 + lr) * K + lc;
  const float* Bptr = Bm + (size_t)(n0 + lr) * K + lc;

  float acc[4][4];
#pragma unroll
  for (int i = 0; i < 4; i++)
#pragma unroll
    for (int j = 0; j < 4; j++) acc[i][j] = 0.f;

  for (int k0 = 0; k0 < K; k0 += 16) {
    const float4 av = *(const float4*)(Aptr + k0);
    const float4 bv = *(const float4*)(Bptr + k0);
    __syncthreads();
    As[lc + 0][lr] = av.x; As[lc + 1][lr] = av.y;
    As[lc + 2][lr] = av.z; As[lc + 3][lr] = av.w;
    Bs[lc + 0][lr] = bv.x; Bs[lc + 1][lr] = bv.y;
    Bs[lc + 2][lr] = bv.z; Bs[lc + 3][lr] = bv.w;
    __syncthreads();
#pragma unroll
    for (int kk = 0; kk < 16; kk++) {
      float a[4], b[4];
      *(float4*)a = *(const float4*)&As[kk][ty << 2];
      *(float4*)b = *(const float4*)&Bs[kk][tx << 2];
#pragma unroll
      for (int i = 0; i < 4; i++)
#pragma unroll
        for (int j = 0; j < 4; j++) acc[i][j] = fmaf(a[i], b[j], acc[i][j]);
    }
  }

  const int m_base = m0 + (ty << 2);
  const int n_base = n0 + (tx << 2);
  const float4 bi4 = *(const float4*)(bias + n_base);
#pragma unroll
  for (int i = 0; i < 4; i++) {
    float4 r;
    r.x = acc[i][0] + bi4.x; r.y = acc[i][1] + bi4.y;
    r.z = acc[i][2] + bi4.z; r.w = acc[i][3] + bi4.w;
    if (RELU) {
      r.x = fmaxf(r.x, 0.f); r.y = fmaxf(r.y, 0.f);
      r.z = fmaxf(r.z, 0.f); r.w = fmaxf(r.w, 0.f);
    }
    *(float4*)(C + (size_t)(m_base + i) * N + n_base) = r;
  }
}

// ---------------- attention: one block per (b,h), one thread per q row ------
__global__ __launch_bounds__(512) void attn_kernel(const float* __restrict__ qkv,
                                                   float* __restrict__ o) {
  const int bh = blockIdx.x;
  const int b = bh >> 3, h = bh & 7;
  const int tid = threadIdx.x;
  __shared__ float Ks[128][32];
  __shared__ float Vs[128][32];
  const float* base = qkv + (size_t)b * S_ * 768;

  float q[32];
  {
    const float* qp = base + (size_t)tid * 768 + h * 32;
#pragma unroll
    for (int i = 0; i < 8; i++) *(float4*)&q[i * 4] = *(const float4*)(qp + i * 4);
  }
  float m = -INFINITY, l = 0.f;
  float acc[32];
#pragma unroll
  for (int d = 0; d < 32; d++) acc[d] = 0.f;
  const float scale = 0.17677669529663687f;  // 1/sqrt(32)

  for (int c0 = 0; c0 < S_; c0 += 128) {
    __syncthreads();
    for (int i = tid; i < 128 * 8; i += 512) {
      const int r = i >> 3, c4 = (i & 7) << 2;
      const float* kp = base + (size_t)(c0 + r) * 768 + 256 + h * 32 + c4;
      *(float4*)&Ks[r][c4] = *(const float4*)kp;
      *(float4*)&Vs[r][c4] = *(const float4*)(kp + 256);
    }
    __syncthreads();
    for (int k = 0; k < 128; k++) {
      float p0 = 0.f, p1 = 0.f, p2 = 0.f, p3 = 0.f;
#pragma unroll
      for (int d = 0; d < 32; d += 4) {
        p0 = fmaf(q[d + 0], Ks[k][d + 0], p0);
        p1 = fmaf(q[d + 1], Ks[k][d + 1], p1);
        p2 = fmaf(q[d + 2], Ks[k][d + 2], p2);
        p3 = fmaf(q[d + 3], Ks[k][d + 3], p3);
      }
      const float dot = ((p0 + p1) + (p2 + p3)) * scale;
      const float mn = fmaxf(m, dot);
      const float corr = __expf(m - mn);
      const float p = __expf(dot - mn);
      l = l * corr + p;
#pragma unroll
      for (int d = 0; d < 32; d++) acc[d] = fmaf(acc[d], corr, p * Vs[k][d]);
      m = mn;
    }
  }
  const float inv = 1.f / l;
  float* op = o + (size_t)(b * S_ + tid) * D_ + h * 32;
#pragma unroll
  for (int i = 0; i < 8; i++) {
    float4 r;
    r.x = acc[i * 4 + 0] * inv; r.y = acc[i * 4 + 1] * inv;
    r.z = acc[i * 4 + 2] * inv; r.w = acc[i * 4 + 3] * inv;
    *(float4*)(op + i * 4) = r;
  }
}

// ---------------- fused residual + layernorm (one wave per row) -------------
__global__ __launch_bounds__(256) void add_ln(const float* __restrict__ x,
                                              const float* __restrict__ y,
                                              const float* __restrict__ g,
                                              const float* __restrict__ bta,
                                              float* __restrict__ out) {
  const int row  = blockIdx.x * 4 + (threadIdx.x >> 6);
  const int lane = threadIdx.x & 63;
  const size_t base = (size_t)row * D_ + lane * 4;
  const float4 xv = *(const float4*)(x + base);
  const float4 yv = *(const float4*)(y + base);
  float v[4] = {xv.x + yv.x, xv.y + yv.y, xv.z + yv.z, xv.w + yv.w};
  float s = v[0] + v[1] + v[2] + v[3];
  s = wave_sum(s);
  const float mean = s * (1.f / 256.f);
  float d[4] = {v[0] - mean, v[1] - mean, v[2] - mean, v[3] - mean};
  float sq = d[0] * d[0] + d[1] * d[1] + d[2] * d[2] + d[3] * d[3];
  sq = wave_sum(sq);
  const float inv = 1.f / sqrtf(sq * (1.f / 256.f) + 1e-5f);
  const float4 gv = *(const float4*)(g + lane * 4);
  const float4 bv = *(const float4*)(bta + lane * 4);
  float4 r;
  r.x = d[0] * inv * gv.x + bv.x; r.y = d[1] * inv * gv.y + bv.y;
  r.z = d[2] * inv * gv.z + bv.z; r.w = d[3] * inv * gv.w + bv.w;
  *(float4*)(out + base) = r;
}

// ---------------- gate logit -> mask ----------------------------------------
__global__ __launch_bounds__(256) void gate_mask(const float* __restrict__ t,
                                                 const float* __restrict__ Wg2,
                                                 const float* __restrict__ bg2,
                                                 int* __restrict__ mask) {
  const int row  = blockIdx.x * 4 + (threadIdx.x >> 6);
  const int lane = threadIdx.x & 63;
  const float4 tv = *(const float4*)(t + (size_t)row * D_ + lane * 4);
  const float4 wv = *(const float4*)(Wg2 + lane * 4);
  float s = tv.x * wv.x + tv.y * wv.y + tv.z * wv.z + tv.w * wv.w;
  s = wave_sum(s);
  if (lane == 0) mask[row] = (s + bg2[0]) > 0.f ? 1 : 0;
}

// ---------------- sequential prefix-scan over 16384 masks -------------------
__global__ __launch_bounds__(256) void scan_kernel(const int* __restrict__ mask,
                                                   int* __restrict__ slots,
                                                   int* __restrict__ countp) {
  __shared__ int ps[256];
  const int tid = threadIdx.x;
  const int base = tid * 64;
  int s = 0;
  for (int i = 0; i < 64; i++) s += mask[base + i];
  ps[tid] = s;
  __syncthreads();
  if (tid == 0) {
    int run = 0;
    for (int i = 0; i < 256; i++) { const int t = ps[i]; ps[i] = run; run += t; }
    countp[0] = run < M_ ? run : M_;
  }
  __syncthreads();
  int run = ps[tid];
  for (int i = 0; i < 64; i++) {
    const int r = base + i;
    const int mk = mask[r];
    slots[r] = (mk && run < M_) ? run : -1;
    run += mk;
  }
}

// ---------------- scatter selected rows into memory -------------------------
__global__ __launch_bounds__(256) void scatter_kernel(const float* __restrict__ h,
                                                      const int* __restrict__ slots,
                                                      float* __restrict__ mem) {
  const int row  = blockIdx.x * 4 + (threadIdx.x >> 6);
  const int lane = threadIdx.x & 63;
  const int sl = slots[row];
  if (sl >= 0)
    *(float4*)(mem + (size_t)sl * D_ + lane * 4) =
        *(const float4*)(h + (size_t)row * D_ + lane * 4);
}

// ---------------- finalize: cosine sims, top-4, mix, classifier -------------
__global__ __launch_bounds__(256) void finalize_kernel(const float* __restrict__ h,
                                                       const float* __restrict__ mem,
                                                       const int* __restrict__ countp,
                                                       const float* __restrict__ Wc,
                                                       const float* __restrict__ bc,
                                                       float* __restrict__ out) {
  __shared__ float cls[256];
  __shared__ float sims[4096];
  __shared__ float rv[256];
  __shared__ int   ri[256];
  __shared__ float aug[256];
  __shared__ float tv[4];
  __shared__ int   tix[4];
  __shared__ float share[1];

  const int b = blockIdx.x, tid = threadIdx.x;
  const int lane = tid & 63, wid = tid >> 6;
  const int count = countp[0];

  const float* crow = h + (size_t)b * S_ * D_;  // row (b*512 + 0)
  if (wid == 0) {
    const float4 c = *(const float4*)(crow + lane * 4);
    *(float4*)&cls[lane * 4] = c;
    float sq = c.x * c.x + c.y * c.y + c.z * c.z + c.w * c.w;
    sq = wave_sum(sq);
    if (lane == 0) share[0] = sqrtf(sq) + 1e-8f;
  }
  __syncthreads();
  const float qden = share[0];

  const float4 c4 = *(const float4*)&cls[lane * 4];
  for (int r = wid; r < M_; r += 4) {
    const float4 m4 = *(const float4*)(mem + (size_t)r * D_ + lane * 4);
    float dt = m4.x * c4.x + m4.y * c4.y + m4.z * c4.z + m4.w * c4.w;
    float sq = m4.x * m4.x + m4.y * m4.y + m4.z * m4.z + m4.w * m4.w;
    dt = wave_sum(dt);
    sq = wave_sum(sq);
    if (lane == 0)
      sims[r] = (r < count) ? dt / (qden * (sqrtf(sq) + 1e-8f)) : -1e9f;
  }
  __syncthreads();

  for (int k = 0; k < 4; k++) {
    float bv = -INFINITY; int bi = 1 << 30;
    for (int r = tid; r < M_; r += 256) {
      const float v = sims[r];
      if (v > bv || (v == bv && r < bi)) { bv = v; bi = r; }
    }
    rv[tid] = bv; ri[tid] = bi;
    __syncthreads();
    if (tid == 0) {
      float bb = rv[0]; int bbi = ri[0];
      for (int i = 1; i < 256; i++)
        if (rv[i] > bb || (rv[i] == bb && ri[i] < bbi)) { bb = rv[i]; bbi = ri[i]; }
      tv[k] = bb; tix[k] = bbi; sims[bbi] = -INFINITY;
    }
    __syncthreads();
  }

  float w[4];
  {
    const float mx = tv[0];
    float ws = 0.f;
#pragma unroll
    for (int k = 0; k < 4; k++) { w[k] = expf(tv[k] - mx); ws += w[k]; }
    const float inv = 1.f / ws;
#pragma unroll
    for (int k = 0; k < 4; k++) w[k] *= inv;
  }

  {
    const int d = tid;
    float mv = 0.f;
    if (count > 0) {
#pragma unroll
      for (int k = 0; k < 4; k++) mv = fmaf(w[k], mem[(size_t)tix[k] * D_ + d], mv);
    }
    aug[d] = cls[d] + mv;
  }
  __syncthreads();

  const float4 a4 = *(const float4*)&aug[lane * 4];
  for (int c = wid; c < NC_; c += 4) {
    const float4 wc = *(const float4*)(Wc + (size_t)c * D_ + lane * 4);
    float dt = a4.x * wc.x + a4.y * wc.y + a4.z * wc.z + a4.w * wc.w;
    dt = wave_sum(dt);
    if (lane == 0) out[b * NC_ + c] = dt + bc[c];
  }
}

// ---------------- launcher ---------------------------------------------------
extern "C" void kernel_launch(void* const* d_in, const int* in_sizes, int n_in,
                              void* d_out, int out_size, void* d_ws, size_t ws_size,
                              hipStream_t stream) {
  const int*   ids  = (const int*)d_in[0];
  const float* tok  = (const float*)d_in[1];
  const float* pos  = (const float*)d_in[2];
  const float* Wqkv = (const float*)d_in[3];
  const float* bqkv = (const float*)d_in[4];
  const float* Wo   = (const float*)d_in[5];
  const float* bo   = (const float*)d_in[6];
  const float* ln1g = (const float*)d_in[7];
  const float* ln1b = (const float*)d_in[8];
  const float* W1   = (const float*)d_in[9];
  const float* b1   = (const float*)d_in[10];
  const float* W2   = (const float*)d_in[11];
  const float* b2   = (const float*)d_in[12];
  const float* ln2g = (const float*)d_in[13];
  const float* ln2b = (const float*)d_in[14];
  const float* Wg1  = (const float*)d_in[15];
  const float* bg1  = (const float*)d_in[16];
  const float* Wg2  = (const float*)d_in[17];
  const float* bg2  = (const float*)d_in[18];
  const float* Wc   = (const float*)d_in[19];
  const float* bc   = (const float*)d_in[20];
  float* out = (float*)d_out;

  float* xA   = (float*)d_ws;
  float* xB   = xA  + (size_t)ROWS * D_;
  float* ob   = xB  + (size_t)ROWS * D_;
  float* pb   = ob  + (size_t)ROWS * D_;
  float* big  = pb  + (size_t)ROWS * D_;
  float* mem  = big + (size_t)ROWS * FF_;
  int*   mask = (int*)(mem + (size_t)M_ * D_);
  int*   slots = mask + ROWS;
  int*   cnt   = slots + ROWS;

  emb_kernel<<<ROWS / 4, 256, 0, stream>>>(ids, tok, pos, xA);

  for (int l = 0; l < L_; l++) {
    gemm_bt<0><<<dim3(768 / 64, ROWS / 64), 256, 0, stream>>>(
        xA, Wqkv + (size_t)l * 768 * 256, bqkv + l * 768, big, ROWS, 768, 256);
    attn_kernel<<<B_ * H_, 512, 0, stream>>>(big, ob);
    gemm_bt<0><<<dim3(256 / 64, ROWS / 64), 256, 0, stream>>>(
        ob, Wo + (size_t)l * 256 * 256, bo + l * 256, pb, ROWS, 256, 256);
    add_ln<<<ROWS / 4, 256, 0, stream>>>(xA, pb, ln1g + l * 256, ln1b + l * 256, xB);
    gemm_bt<1><<<dim3(1024 / 64, ROWS / 64), 256, 0, stream>>>(
        xB, W1 + (size_t)l * 1024 * 256, b1 + l * 1024, big, ROWS, 1024, 256);
    gemm_bt<0><<<dim3(256 / 64, ROWS / 64), 256, 0, stream>>>(
        big, W2 + (size_t)l * 256 * 1024, b2 + l * 256, pb, ROWS, 256, 1024);
    add_ln<<<ROWS / 4, 256, 0, stream>>>(xB, pb, ln2g + l * 256, ln2b + l * 256, xA);
  }

  // gate MLP: t = relu(h @ Wg1^T + bg1)  -> mask
  gemm_bt<1><<<dim3(256 / 64, ROWS / 64), 256, 0, stream>>>(
      xA, Wg1, bg1, ob, ROWS, 256, 256);
  gate_mask<<<ROWS / 4, 256, 0, stream>>>(ob, Wg2, bg2, mask);
  scan_kernel<<<1, 256, 0, stream>>>(mask, slots, cnt);
  (void)hipMemsetAsync(mem, 0, (size_t)M_ * D_ * sizeof(float), stream);
  scatter_kernel<<<ROWS / 4, 256, 0, stream>>>(xA, slots, mem);
  finalize_kernel<<<B_, 256, 0, stream>>>(xA, mem, cnt, Wc, bc, out);
}

// Round 2
// 1789.826 us; speedup vs baseline: 1.3214x; 1.3214x over previous
//
#include <hip/hip_runtime.h>
#include <math.h>

#define D_   256
#define H_   8
#define L_   2
#define FF_  1024
#define S_   512
#define B_   32
#define M_   4096
#define NC_  10
#define ROWS (B_*S_)   // 16384

__device__ __forceinline__ float wave_sum(float v) {
#pragma unroll
  for (int off = 1; off < 64; off <<= 1) v += __shfl_xor(v, off, 64);
  return v;
}

// ---------------- embedding ----------------
__global__ __launch_bounds__(256) void emb_kernel(const int* __restrict__ ids,
                                                  const float* __restrict__ tok,
                                                  const float* __restrict__ pos,
                                                  float* __restrict__ x) {
  const int row  = blockIdx.x * 4 + (threadIdx.x >> 6);
  const int lane = threadIdx.x & 63;
  const int id = ids[row];
  const int s  = row & (S_ - 1);
  const float4 t = *(const float4*)(tok + (size_t)id * D_ + lane * 4);
  const float4 p = *(const float4*)(pos + (size_t)s  * D_ + lane * 4);
  float4 r; r.x = t.x + p.x; r.y = t.y + p.y; r.z = t.z + p.z; r.w = t.w + p.w;
  *(float4*)(x + (size_t)row * D_ + lane * 4) = r;
}

// ---- GEMM: C[M,N] = A[M,K] * B[N,K]^T + bias (+ReLU), 128x128 tile, BK=16 --
// 512 threads: tx=tid&31 (4 cols), ty=tid>>5 (rows ty*4..+3 and +64)
template<int RELU>
__global__ __launch_bounds__(512) void gemm_bt(const float* __restrict__ A,
                                               const float* __restrict__ Bm,
                                               const float* __restrict__ bias,
                                               float* __restrict__ C,
                                               int M, int N, int K) {
  __shared__ float As[16][132];
  __shared__ float Bs[16][132];
  const int tid = threadIdx.x;
  const int tx = tid & 31, ty = tid >> 5;
  const int tx4 = tx << 2, ty4 = ty << 2;
  const int m0 = blockIdx.y * 128, n0 = blockIdx.x * 128;
  const int lrow = tid >> 2;           // 0..127 tile row to stage
  const int kq   = (tid & 3) << 2;     // 0,4,8,12 k offset
  const float* Aptr = A + (size_t)(m0 + lrow) * K + kq;
  const float* Bptr = Bm + (size_t)(n0 + lrow) * K + kq;

  float acc[8][4];
#pragma unroll
  for (int i = 0; i < 8; i++)
#pragma unroll
    for (int j = 0; j < 4; j++) acc[i][j] = 0.f;

  for (int k0 = 0; k0 < K; k0 += 16) {
    const float4 av = *(const float4*)(Aptr + k0);
    const float4 bv = *(const float4*)(Bptr + k0);
    __syncthreads();
    As[kq + 0][lrow] = av.x; As[kq + 1][lrow] = av.y;
    As[kq + 2][lrow] = av.z; As[kq + 3][lrow] = av.w;
    Bs[kq + 0][lrow] = bv.x; Bs[kq + 1][lrow] = bv.y;
    Bs[kq + 2][lrow] = bv.z; Bs[kq + 3][lrow] = bv.w;
    __syncthreads();
#pragma unroll
    for (int kk = 0; kk < 16; kk++) {
      float a0[4], a1[4], b0[4];
      *(float4*)a0 = *(const float4*)&As[kk][ty4];
      *(float4*)a1 = *(const float4*)&As[kk][ty4 + 64];
      *(float4*)b0 = *(const float4*)&Bs[kk][tx4];
#pragma unroll
      for (int i = 0; i < 4; i++)
#pragma unroll
        for (int j = 0; j < 4; j++) {
          acc[i][j]     = fmaf(a0[i], b0[j], acc[i][j]);
          acc[4 + i][j] = fmaf(a1[i], b0[j], acc[4 + i][j]);
        }
    }
  }

  const float4 bi4 = *(const float4*)(bias + n0 + tx4);
#pragma unroll
  for (int g = 0; g < 2; g++) {
    const int mb = m0 + g * 64 + ty4;
#pragma unroll
    for (int i = 0; i < 4; i++) {
      float4 r;
      r.x = acc[g * 4 + i][0] + bi4.x; r.y = acc[g * 4 + i][1] + bi4.y;
      r.z = acc[g * 4 + i][2] + bi4.z; r.w = acc[g * 4 + i][3] + bi4.w;
      if (RELU) {
        r.x = fmaxf(r.x, 0.f); r.y = fmaxf(r.y, 0.f);
        r.z = fmaxf(r.z, 0.f); r.w = fmaxf(r.w, 0.f);
      }
      *(float4*)(C + (size_t)(mb + i) * N + n0 + tx4) = r;
    }
  }
}

// ---------------- attention: one block per (b,h), one thread per q row ------
__global__ __launch_bounds__(512) void attn_kernel(const float* __restrict__ qkv,
                                                   float* __restrict__ o) {
  const int bh = blockIdx.x;
  const int b = bh >> 3, h = bh & 7;
  const int tid = threadIdx.x;
  __shared__ float Ks[128][32];
  __shared__ float Vs[128][32];
  const float* base = qkv + (size_t)b * S_ * 768;

  float q[32];
  {
    const float* qp = base + (size_t)tid * 768 + h * 32;
#pragma unroll
    for (int i = 0; i < 8; i++) *(float4*)&q[i * 4] = *(const float4*)(qp + i * 4);
  }
  float m = -INFINITY, l = 0.f;
  float acc[32];
#pragma unroll
  for (int d = 0; d < 32; d++) acc[d] = 0.f;
  const float scale = 0.17677669529663687f;  // 1/sqrt(32)

  for (int c0 = 0; c0 < S_; c0 += 128) {
    __syncthreads();
    for (int i = tid; i < 128 * 8; i += 512) {
      const int r = i >> 3, c4 = (i & 7) << 2;
      const float* kp = base + (size_t)(c0 + r) * 768 + 256 + h * 32 + c4;
      *(float4*)&Ks[r][c4] = *(const float4*)kp;
      *(float4*)&Vs[r][c4] = *(const float4*)(kp + 256);
    }
    __syncthreads();
    for (int k = 0; k < 128; k++) {
      float p0 = 0.f, p1 = 0.f, p2 = 0.f, p3 = 0.f;
#pragma unroll
      for (int d = 0; d < 32; d += 4) {
        p0 = fmaf(q[d + 0], Ks[k][d + 0], p0);
        p1 = fmaf(q[d + 1], Ks[k][d + 1], p1);
        p2 = fmaf(q[d + 2], Ks[k][d + 2], p2);
        p3 = fmaf(q[d + 3], Ks[k][d + 3], p3);
      }
      const float dot = ((p0 + p1) + (p2 + p3)) * scale;
      const float mn = fmaxf(m, dot);
      const float corr = __expf(m - mn);
      const float p = __expf(dot - mn);
      l = l * corr + p;
#pragma unroll
      for (int d = 0; d < 32; d++) acc[d] = fmaf(acc[d], corr, p * Vs[k][d]);
      m = mn;
    }
  }
  const float inv = 1.f / l;
  float* op = o + (size_t)(b * S_ + tid) * D_ + h * 32;
#pragma unroll
  for (int i = 0; i < 8; i++) {
    float4 r;
    r.x = acc[i * 4 + 0] * inv; r.y = acc[i * 4 + 1] * inv;
    r.z = acc[i * 4 + 2] * inv; r.w = acc[i * 4 + 3] * inv;
    *(float4*)(op + i * 4) = r;
  }
}

// ---------------- fused residual + layernorm (one wave per row) -------------
__global__ __launch_bounds__(256) void add_ln(const float* __restrict__ x,
                                              const float* __restrict__ y,
                                              const float* __restrict__ g,
                                              const float* __restrict__ bta,
                                              float* __restrict__ out) {
  const int row  = blockIdx.x * 4 + (threadIdx.x >> 6);
  const int lane = threadIdx.x & 63;
  const size_t base = (size_t)row * D_ + lane * 4;
  const float4 xv = *(const float4*)(x + base);
  const float4 yv = *(const float4*)(y + base);
  float v[4] = {xv.x + yv.x, xv.y + yv.y, xv.z + yv.z, xv.w + yv.w};
  float s = v[0] + v[1] + v[2] + v[3];
  s = wave_sum(s);
  const float mean = s * (1.f / 256.f);
  float d[4] = {v[0] - mean, v[1] - mean, v[2] - mean, v[3] - mean};
  float sq = d[0] * d[0] + d[1] * d[1] + d[2] * d[2] + d[3] * d[3];
  sq = wave_sum(sq);
  const float inv = 1.f / sqrtf(sq * (1.f / 256.f) + 1e-5f);
  const float4 gv = *(const float4*)(g + lane * 4);
  const float4 bv = *(const float4*)(bta + lane * 4);
  float4 r;
  r.x = d[0] * inv * gv.x + bv.x; r.y = d[1] * inv * gv.y + bv.y;
  r.z = d[2] * inv * gv.z + bv.z; r.w = d[3] * inv * gv.w + bv.w;
  *(float4*)(out + base) = r;
}

// ---------------- gate logit -> mask ----------------------------------------
__global__ __launch_bounds__(256) void gate_mask(const float* __restrict__ t,
                                                 const float* __restrict__ Wg2,
                                                 const float* __restrict__ bg2,
                                                 int* __restrict__ mask) {
  const int row  = blockIdx.x * 4 + (threadIdx.x >> 6);
  const int lane = threadIdx.x & 63;
  const float4 tv = *(const float4*)(t + (size_t)row * D_ + lane * 4);
  const float4 wv = *(const float4*)(Wg2 + lane * 4);
  float s = tv.x * wv.x + tv.y * wv.y + tv.z * wv.z + tv.w * wv.w;
  s = wave_sum(s);
  if (lane == 0) mask[row] = (s + bg2[0]) > 0.f ? 1 : 0;
}

// ---------------- sequential prefix-scan over 16384 masks -------------------
__global__ __launch_bounds__(256) void scan_kernel(const int* __restrict__ mask,
                                                   int* __restrict__ slots,
                                                   int* __restrict__ countp) {
  __shared__ int ps[256];
  const int tid = threadIdx.x;
  const int base = tid * 64;
  int s = 0;
  for (int i = 0; i < 64; i++) s += mask[base + i];
  ps[tid] = s;
  __syncthreads();
  if (tid == 0) {
    int run = 0;
    for (int i = 0; i < 256; i++) { const int t = ps[i]; ps[i] = run; run += t; }
    countp[0] = run < M_ ? run : M_;
  }
  __syncthreads();
  int run = ps[tid];
  for (int i = 0; i < 64; i++) {
    const int r = base + i;
    const int mk = mask[r];
    slots[r] = (mk && run < M_) ? run : -1;
    run += mk;
  }
}

// ---------------- scatter selected rows into memory -------------------------
__global__ __launch_bounds__(256) void scatter_kernel(const float* __restrict__ h,
                                                      const int* __restrict__ slots,
                                                      float* __restrict__ mem) {
  const int row  = blockIdx.x * 4 + (threadIdx.x >> 6);
  const int lane = threadIdx.x & 63;
  const int sl = slots[row];
  if (sl >= 0)
    *(float4*)(mem + (size_t)sl * D_ + lane * 4) =
        *(const float4*)(h + (size_t)row * D_ + lane * 4);
}

// ---------------- query norms (one wave per batch row) ----------------------
__global__ __launch_bounds__(256) void qnorm_kernel(const float* __restrict__ h,
                                                    float* __restrict__ qden) {
  const int b    = blockIdx.x * 4 + (threadIdx.x >> 6);
  const int lane = threadIdx.x & 63;
  const float4 c = *(const float4*)(h + (size_t)b * S_ * D_ + lane * 4);
  float sq = c.x * c.x + c.y * c.y + c.z * c.z + c.w * c.w;
  sq = wave_sum(sq);
  if (lane == 0) qden[b] = sqrtf(sq) + 1e-8f;
}

// ------- sims[b][r] for all 32 b: one wave per memory row r -----------------
__global__ __launch_bounds__(256) void sims_kernel(const float* __restrict__ h,
                                                   const float* __restrict__ mem,
                                                   const float* __restrict__ qden,
                                                   const int* __restrict__ countp,
                                                   float* __restrict__ sims) {
  __shared__ float cls[B_ * D_];
  __shared__ float qd[B_];
  const int tid = threadIdx.x;
  const int lane = tid & 63, wid = tid >> 6;
  for (int i = tid; i < B_ * D_ / 4; i += 256) {
    const int flat = i * 4;
    const int b = flat >> 8, d = flat & 255;
    *(float4*)&cls[flat] = *(const float4*)(h + (size_t)b * S_ * D_ + d);
  }
  if (tid < B_) qd[tid] = qden[tid];
  __syncthreads();
  const int count = countp[0];
  const int r = blockIdx.x * 4 + wid;
  const float4 m4 = *(const float4*)(mem + (size_t)r * D_ + lane * 4);
  float sq = m4.x * m4.x + m4.y * m4.y + m4.z * m4.z + m4.w * m4.w;
  sq = wave_sum(sq);
  const float rn = sqrtf(sq) + 1e-8f;
  if (r < count) {
    for (int b = 0; b < B_; b++) {
      const float4 c4 = *(const float4*)&cls[b * D_ + lane * 4];
      float dt = m4.x * c4.x + m4.y * c4.y + m4.z * c4.z + m4.w * c4.w;
      dt = wave_sum(dt);
      if (lane == 0) sims[b * M_ + r] = dt / (qd[b] * rn);
    }
  } else if (lane == 0) {
    for (int b = 0; b < B_; b++) sims[b * M_ + r] = -1e9f;
  }
}

// ---------------- per-batch: top-4, softmax mix, classifier -----------------
__global__ __launch_bounds__(256) void topk_mix(const float* __restrict__ h,
                                                const float* __restrict__ mem,
                                                const float* __restrict__ simsg,
                                                const int* __restrict__ countp,
                                                const float* __restrict__ Wc,
                                                const float* __restrict__ bc,
                                                float* __restrict__ out) {
  __shared__ float sims[M_];
  __shared__ float cls[D_];
  __shared__ float rv[256];
  __shared__ int   ri[256];
  __shared__ float aug[D_];
  __shared__ float tv[4];
  __shared__ int   tix[4];

  const int b = blockIdx.x, tid = threadIdx.x;
  const int lane = tid & 63, wid = tid >> 6;
  const int count = countp[0];

  for (int i = tid; i < M_; i += 256) sims[i] = simsg[b * M_ + i];
  cls[tid] = h[(size_t)b * S_ * D_ + tid];
  __syncthreads();

  for (int k = 0; k < 4; k++) {
    float bv = -INFINITY; int bi = 1 << 30;
    for (int r = tid; r < M_; r += 256) {
      const float v = sims[r];
      if (v > bv || (v == bv && r < bi)) { bv = v; bi = r; }
    }
    rv[tid] = bv; ri[tid] = bi;
    __syncthreads();
    if (tid == 0) {
      float bb = rv[0]; int bbi = ri[0];
      for (int i = 1; i < 256; i++)
        if (rv[i] > bb || (rv[i] == bb && ri[i] < bbi)) { bb = rv[i]; bbi = ri[i]; }
      tv[k] = bb; tix[k] = bbi; sims[bbi] = -INFINITY;
    }
    __syncthreads();
  }

  float w[4];
  {
    const float mx = tv[0];
    float ws = 0.f;
#pragma unroll
    for (int k = 0; k < 4; k++) { w[k] = expf(tv[k] - mx); ws += w[k]; }
    const float inv = 1.f / ws;
#pragma unroll
    for (int k = 0; k < 4; k++) w[k] *= inv;
  }

  {
    float mv = 0.f;
    if (count > 0) {
#pragma unroll
      for (int k = 0; k < 4; k++) mv = fmaf(w[k], mem[(size_t)tix[k] * D_ + tid], mv);
    }
    aug[tid] = cls[tid] + mv;
  }
  __syncthreads();

  const float4 a4 = *(const float4*)&aug[lane * 4];
  for (int c = wid; c < NC_; c += 4) {
    const float4 wc = *(const float4*)(Wc + (size_t)c * D_ + lane * 4);
    float dt = a4.x * wc.x + a4.y * wc.y + a4.z * wc.z + a4.w * wc.w;
    dt = wave_sum(dt);
    if (lane == 0) out[b * NC_ + c] = dt + bc[c];
  }
}

// ---------------- launcher ---------------------------------------------------
extern "C" void kernel_launch(void* const* d_in, const int* in_sizes, int n_in,
                              void* d_out, int out_size, void* d_ws, size_t ws_size,
                              hipStream_t stream) {
  const int*   ids  = (const int*)d_in[0];
  const float* tok  = (const float*)d_in[1];
  const float* pos  = (const float*)d_in[2];
  const float* Wqkv = (const float*)d_in[3];
  const float* bqkv = (const float*)d_in[4];
  const float* Wo   = (const float*)d_in[5];
  const float* bo   = (const float*)d_in[6];
  const float* ln1g = (const float*)d_in[7];
  const float* ln1b = (const float*)d_in[8];
  const float* W1   = (const float*)d_in[9];
  const float* b1   = (const float*)d_in[10];
  const float* W2   = (const float*)d_in[11];
  const float* b2   = (const float*)d_in[12];
  const float* ln2g = (const float*)d_in[13];
  const float* ln2b = (const float*)d_in[14];
  const float* Wg1  = (const float*)d_in[15];
  const float* bg1  = (const float*)d_in[16];
  const float* Wg2  = (const float*)d_in[17];
  const float* bg2  = (const float*)d_in[18];
  const float* Wc   = (const float*)d_in[19];
  const float* bc   = (const float*)d_in[20];
  float* out = (float*)d_out;

  float* xA   = (float*)d_ws;
  float* xB   = xA  + (size_t)ROWS * D_;
  float* ob   = xB  + (size_t)ROWS * D_;
  float* pb   = ob  + (size_t)ROWS * D_;
  float* big  = pb  + (size_t)ROWS * D_;
  float* mem  = big + (size_t)ROWS * FF_;
  float* qden = mem + (size_t)M_ * D_;
  float* sims = qden + 64;
  int*   mask = (int*)(sims + (size_t)B_ * M_);
  int*   slots = mask + ROWS;
  int*   cnt   = slots + ROWS;

  emb_kernel<<<ROWS / 4, 256, 0, stream>>>(ids, tok, pos, xA);

  for (int l = 0; l < L_; l++) {
    gemm_bt<0><<<dim3(768 / 128, ROWS / 128), 512, 0, stream>>>(
        xA, Wqkv + (size_t)l * 768 * 256, bqkv + l * 768, big, ROWS, 768, 256);
    attn_kernel<<<B_ * H_, 512, 0, stream>>>(big, ob);
    gemm_bt<0><<<dim3(256 / 128, ROWS / 128), 512, 0, stream>>>(
        ob, Wo + (size_t)l * 256 * 256, bo + l * 256, pb, ROWS, 256, 256);
    add_ln<<<ROWS / 4, 256, 0, stream>>>(xA, pb, ln1g + l * 256, ln1b + l * 256, xB);
    gemm_bt<1><<<dim3(1024 / 128, ROWS / 128), 512, 0, stream>>>(
        xB, W1 + (size_t)l * 1024 * 256, b1 + l * 1024, big, ROWS, 1024, 256);
    gemm_bt<0><<<dim3(256 / 128, ROWS / 128), 512, 0, stream>>>(
        big, W2 + (size_t)l * 256 * 1024, b2 + l * 256, pb, ROWS, 256, 1024);
    add_ln<<<ROWS / 4, 256, 0, stream>>>(xB, pb, ln2g + l * 256, ln2b + l * 256, xA);
  }

  // gate MLP: t = relu(h @ Wg1^T + bg1)  -> mask
  gemm_bt<1><<<dim3(256 / 128, ROWS / 128), 512, 0, stream>>>(
      xA, Wg1, bg1, ob, ROWS, 256, 256);
  gate_mask<<<ROWS / 4, 256, 0, stream>>>(ob, Wg2, bg2, mask);
  scan_kernel<<<1, 256, 0, stream>>>(mask, slots, cnt);
  (void)hipMemsetAsync(mem, 0, (size_t)M_ * D_ * sizeof(float), stream);
  scatter_kernel<<<ROWS / 4, 256, 0, stream>>>(xA, slots, mem);

  qnorm_kernel<<<B_ / 4, 256, 0, stream>>>(xA, qden);
  sims_kernel<<<M_ / 4, 256, 0, stream>>>(xA, mem, qden, cnt, sims);
  topk_mix<<<B_, 256, 0, stream>>>(xA, mem, sims, cnt, Wc, bc, out);
}

// Round 3
// 1337.451 us; speedup vs baseline: 1.7684x; 1.3382x over previous
//
#include <hip/hip_runtime.h>
#include <math.h>

#define D_   256
#define H_   8
#define L_   2
#define FF_  1024
#define S_   512
#define B_   32
#define M_   4096
#define NC_  10
#define ROWS (B_*S_)   // 16384

__device__ __forceinline__ float wave_sum(float v) {
#pragma unroll
  for (int off = 1; off < 64; off <<= 1) v += __shfl_xor(v, off, 64);
  return v;
}

// ---------------- embedding ----------------
__global__ __launch_bounds__(256) void emb_kernel(const int* __restrict__ ids,
                                                  const float* __restrict__ tok,
                                                  const float* __restrict__ pos,
                                                  float* __restrict__ x) {
  const int row  = blockIdx.x * 4 + (threadIdx.x >> 6);
  const int lane = threadIdx.x & 63;
  const int id = ids[row];
  const int s  = row & (S_ - 1);
  const float4 t = *(const float4*)(tok + (size_t)id * D_ + lane * 4);
  const float4 p = *(const float4*)(pos + (size_t)s  * D_ + lane * 4);
  float4 r; r.x = t.x + p.x; r.y = t.y + p.y; r.z = t.z + p.z; r.w = t.w + p.w;
  *(float4*)(x + (size_t)row * D_ + lane * 4) = r;
}

// ---- GEMM: C[M,N] = A[M,K] * B[N,K]^T + bias (+ReLU), 128x128 tile, BK=16 --
template<int RELU>
__global__ __launch_bounds__(512) void gemm_bt(const float* __restrict__ A,
                                               const float* __restrict__ Bm,
                                               const float* __restrict__ bias,
                                               float* __restrict__ C,
                                               int M, int N, int K) {
  __shared__ float As[16][132];
  __shared__ float Bs[16][132];
  const int tid = threadIdx.x;
  const int tx = tid & 31, ty = tid >> 5;
  const int tx4 = tx << 2, ty4 = ty << 2;
  const int m0 = blockIdx.y * 128, n0 = blockIdx.x * 128;
  const int lrow = tid >> 2;           // 0..127 tile row to stage
  const int kq   = (tid & 3) << 2;     // 0,4,8,12 k offset
  const float* Aptr = A + (size_t)(m0 + lrow) * K + kq;
  const float* Bptr = Bm + (size_t)(n0 + lrow) * K + kq;

  float acc[8][4];
#pragma unroll
  for (int i = 0; i < 8; i++)
#pragma unroll
    for (int j = 0; j < 4; j++) acc[i][j] = 0.f;

  for (int k0 = 0; k0 < K; k0 += 16) {
    const float4 av = *(const float4*)(Aptr + k0);
    const float4 bv = *(const float4*)(Bptr + k0);
    __syncthreads();
    As[kq + 0][lrow] = av.x; As[kq + 1][lrow] = av.y;
    As[kq + 2][lrow] = av.z; As[kq + 3][lrow] = av.w;
    Bs[kq + 0][lrow] = bv.x; Bs[kq + 1][lrow] = bv.y;
    Bs[kq + 2][lrow] = bv.z; Bs[kq + 3][lrow] = bv.w;
    __syncthreads();
#pragma unroll
    for (int kk = 0; kk < 16; kk++) {
      float a0[4], a1[4], b0[4];
      *(float4*)a0 = *(const float4*)&As[kk][ty4];
      *(float4*)a1 = *(const float4*)&As[kk][ty4 + 64];
      *(float4*)b0 = *(const float4*)&Bs[kk][tx4];
#pragma unroll
      for (int i = 0; i < 4; i++)
#pragma unroll
        for (int j = 0; j < 4; j++) {
          acc[i][j]     = fmaf(a0[i], b0[j], acc[i][j]);
          acc[4 + i][j] = fmaf(a1[i], b0[j], acc[4 + i][j]);
        }
    }
  }

  const float4 bi4 = *(const float4*)(bias + n0 + tx4);
#pragma unroll
  for (int g = 0; g < 2; g++) {
    const int mb = m0 + g * 64 + ty4;
#pragma unroll
    for (int i = 0; i < 4; i++) {
      float4 r;
      r.x = acc[g * 4 + i][0] + bi4.x; r.y = acc[g * 4 + i][1] + bi4.y;
      r.z = acc[g * 4 + i][2] + bi4.z; r.w = acc[g * 4 + i][3] + bi4.w;
      if (RELU) {
        r.x = fmaxf(r.x, 0.f); r.y = fmaxf(r.y, 0.f);
        r.z = fmaxf(r.z, 0.f); r.w = fmaxf(r.w, 0.f);
      }
      *(float4*)(C + (size_t)(mb + i) * N + n0 + tx4) = r;
    }
  }
}

// ---------------- attention: block per (b,h), 1024 threads ------------------
// tid = half*512 + q : half 0 handles k in [0,256), half 1 k in [256,512).
// Per-thread online softmax over its half, chunked-max (8 k's per rescale),
// then the two halves' (m, l, acc[32]) are merged through LDS.
#define SCH 8
__global__ __launch_bounds__(1024, 4) void attn_kernel(const float* __restrict__ qkv,
                                                       float* __restrict__ o) {
  __shared__ float smem[8192];           // 32 KB
  float* Ks = smem;                      // [half][64][32]
  float* Vs = smem + 4096;               // [half][64][32]
  const int bh = blockIdx.x;
  const int b = bh >> 3, h = bh & 7;
  const int tid = threadIdx.x;
  const int half = tid >> 9;
  const int q = tid & 511;
  const float* base = qkv + (size_t)b * (S_ * 768);

  float qr[32];
  {
    const float* qp = base + (size_t)q * 768 + h * 32;
#pragma unroll
    for (int i = 0; i < 8; i++) *(float4*)&qr[i * 4] = *(const float4*)(qp + i * 4);
  }
  float m = -INFINITY, l = 0.f;
  float acc[32];
#pragma unroll
  for (int d = 0; d < 32; d++) acc[d] = 0.f;
  const float scale = 0.17677669529663687f;  // 1/sqrt(32)

  for (int t = 0; t < 4; t++) {
    __syncthreads();
    // stage 64 k-rows per half of K and V: 2048 float4, 2 per thread
#pragma unroll
    for (int jj = 0; jj < 2; jj++) {
      const int j  = tid + jj * 1024;
      const int hf = j >> 10;            // which half's chunk
      const int kv = (j >> 9) & 1;       // 0=K, 1=V
      const int r  = (j >> 3) & 63;      // row 0..63
      const int c4 = (j & 7) << 2;
      const float* src = base + (size_t)(hf * 256 + t * 64 + r) * 768 + 256 + kv * 256 + h * 32 + c4;
      float* dst = (kv ? Vs : Ks) + hf * 2048 + r * 32 + c4;
      *(float4*)dst = *(const float4*)src;
    }
    __syncthreads();
    const float* Kh = Ks + half * 2048;
    const float* Vh = Vs + half * 2048;
    for (int c0 = 0; c0 < 64; c0 += SCH) {
      float s[SCH];
#pragma unroll
      for (int j = 0; j < SCH; j++) {
        const float* kp = Kh + (c0 + j) * 32;
        float p0 = 0.f, p1 = 0.f, p2 = 0.f, p3 = 0.f;
#pragma unroll
        for (int d = 0; d < 32; d += 4) {
          p0 = fmaf(qr[d + 0], kp[d + 0], p0);
          p1 = fmaf(qr[d + 1], kp[d + 1], p1);
          p2 = fmaf(qr[d + 2], kp[d + 2], p2);
          p3 = fmaf(qr[d + 3], kp[d + 3], p3);
        }
        s[j] = ((p0 + p1) + (p2 + p3)) * scale;
      }
      float cm = s[0];
#pragma unroll
      for (int j = 1; j < SCH; j++) cm = fmaxf(cm, s[j]);
      const float mn = fmaxf(m, cm);
      const float corr = __expf(m - mn);
      m = mn;
      l *= corr;
#pragma unroll
      for (int d = 0; d < 32; d++) acc[d] *= corr;
#pragma unroll
      for (int j = 0; j < SCH; j++) {
        const float p = __expf(s[j] - mn);
        l += p;
        const float* vp = Vh + (c0 + j) * 32;
#pragma unroll
        for (int d = 0; d < 32; d++) acc[d] = fmaf(p, vp[d], acc[d]);
      }
    }
  }

  // ---- merge the two halves ----
  __syncthreads();
  smem[tid * 2] = m; smem[tid * 2 + 1] = l;
  __syncthreads();
  const int partner = tid ^ 512;
  const float m2 = smem[partner * 2], l2 = smem[partner * 2 + 1];
  const float ms = fmaxf(m, m2);
  const float a1 = __expf(m - ms);    // my scale
  const float a2 = __expf(m2 - ms);   // partner scale
  const float lt = l * a1 + l2 * a2;
  __syncthreads();

  float* op = o + (size_t)(b * S_ + q) * D_ + h * 32;
  const float inv = 1.f / lt;
  float* ab = smem;                    // [512][16] per phase
#pragma unroll
  for (int ph = 0; ph < 2; ph++) {
    if (half == 1) {
#pragma unroll
      for (int d4 = 0; d4 < 16; d4 += 4)
        *(float4*)&ab[q * 16 + d4] = *(const float4*)&acc[ph * 16 + d4];
    }
    __syncthreads();
    if (half == 0) {
#pragma unroll
      for (int d4 = 0; d4 < 16; d4 += 4) {
        const float4 pv = *(const float4*)&ab[q * 16 + d4];
        float4 r;
        r.x = (acc[ph * 16 + d4 + 0] * a1 + pv.x * a2) * inv;
        r.y = (acc[ph * 16 + d4 + 1] * a1 + pv.y * a2) * inv;
        r.z = (acc[ph * 16 + d4 + 2] * a1 + pv.z * a2) * inv;
        r.w = (acc[ph * 16 + d4 + 3] * a1 + pv.w * a2) * inv;
        *(float4*)(op + ph * 16 + d4) = r;
      }
    }
    __syncthreads();
  }
}

// ---------------- fused residual + layernorm (one wave per row) -------------
__global__ __launch_bounds__(256) void add_ln(const float* __restrict__ x,
                                              const float* __restrict__ y,
                                              const float* __restrict__ g,
                                              const float* __restrict__ bta,
                                              float* __restrict__ out) {
  const int row  = blockIdx.x * 4 + (threadIdx.x >> 6);
  const int lane = threadIdx.x & 63;
  const size_t base = (size_t)row * D_ + lane * 4;
  const float4 xv = *(const float4*)(x + base);
  const float4 yv = *(const float4*)(y + base);
  float v[4] = {xv.x + yv.x, xv.y + yv.y, xv.z + yv.z, xv.w + yv.w};
  float s = v[0] + v[1] + v[2] + v[3];
  s = wave_sum(s);
  const float mean = s * (1.f / 256.f);
  float d[4] = {v[0] - mean, v[1] - mean, v[2] - mean, v[3] - mean};
  float sq = d[0] * d[0] + d[1] * d[1] + d[2] * d[2] + d[3] * d[3];
  sq = wave_sum(sq);
  const float inv = 1.f / sqrtf(sq * (1.f / 256.f) + 1e-5f);
  const float4 gv = *(const float4*)(g + lane * 4);
  const float4 bv = *(const float4*)(bta + lane * 4);
  float4 r;
  r.x = d[0] * inv * gv.x + bv.x; r.y = d[1] * inv * gv.y + bv.y;
  r.z = d[2] * inv * gv.z + bv.z; r.w = d[3] * inv * gv.w + bv.w;
  *(float4*)(out + base) = r;
}

// ---------------- gate logit -> mask ----------------------------------------
__global__ __launch_bounds__(256) void gate_mask(const float* __restrict__ t,
                                                 const float* __restrict__ Wg2,
                                                 const float* __restrict__ bg2,
                                                 int* __restrict__ mask) {
  const int row  = blockIdx.x * 4 + (threadIdx.x >> 6);
  const int lane = threadIdx.x & 63;
  const float4 tv = *(const float4*)(t + (size_t)row * D_ + lane * 4);
  const float4 wv = *(const float4*)(Wg2 + lane * 4);
  float s = tv.x * wv.x + tv.y * wv.y + tv.z * wv.z + tv.w * wv.w;
  s = wave_sum(s);
  if (lane == 0) mask[row] = (s + bg2[0]) > 0.f ? 1 : 0;
}

// ---------------- sequential prefix-scan over 16384 masks -------------------
__global__ __launch_bounds__(256) void scan_kernel(const int* __restrict__ mask,
                                                   int* __restrict__ slots,
                                                   int* __restrict__ countp) {
  __shared__ int ps[256];
  const int tid = threadIdx.x;
  const int base = tid * 64;
  int s = 0;
  for (int i = 0; i < 64; i++) s += mask[base + i];
  ps[tid] = s;
  __syncthreads();
  if (tid == 0) {
    int run = 0;
    for (int i = 0; i < 256; i++) { const int t = ps[i]; ps[i] = run; run += t; }
    countp[0] = run < M_ ? run : M_;
  }
  __syncthreads();
  int run = ps[tid];
  for (int i = 0; i < 64; i++) {
    const int r = base + i;
    const int mk = mask[r];
    slots[r] = (mk && run < M_) ? run : -1;
    run += mk;
  }
}

// ---------------- scatter selected rows into memory -------------------------
__global__ __launch_bounds__(256) void scatter_kernel(const float* __restrict__ h,
                                                      const int* __restrict__ slots,
                                                      float* __restrict__ mem) {
  const int row  = blockIdx.x * 4 + (threadIdx.x >> 6);
  const int lane = threadIdx.x & 63;
  const int sl = slots[row];
  if (sl >= 0)
    *(float4*)(mem + (size_t)sl * D_ + lane * 4) =
        *(const float4*)(h + (size_t)row * D_ + lane * 4);
}

// ---------------- query norms (one wave per batch row) ----------------------
__global__ __launch_bounds__(256) void qnorm_kernel(const float* __restrict__ h,
                                                    float* __restrict__ qden) {
  const int b    = blockIdx.x * 4 + (threadIdx.x >> 6);
  const int lane = threadIdx.x & 63;
  const float4 c = *(const float4*)(h + (size_t)b * S_ * D_ + lane * 4);
  float sq = c.x * c.x + c.y * c.y + c.z * c.z + c.w * c.w;
  sq = wave_sum(sq);
  if (lane == 0) qden[b] = sqrtf(sq) + 1e-8f;
}

// ------- sims[b][r] for all 32 b: one wave per memory row r -----------------
__global__ __launch_bounds__(256) void sims_kernel(const float* __restrict__ h,
                                                   const float* __restrict__ mem,
                                                   const float* __restrict__ qden,
                                                   const int* __restrict__ countp,
                                                   float* __restrict__ sims) {
  __shared__ float cls[B_ * D_];
  __shared__ float qd[B_];
  const int tid = threadIdx.x;
  const int lane = tid & 63, wid = tid >> 6;
  for (int i = tid; i < B_ * D_ / 4; i += 256) {
    const int flat = i * 4;
    const int b = flat >> 8, d = flat & 255;
    *(float4*)&cls[flat] = *(const float4*)(h + (size_t)b * S_ * D_ + d);
  }
  if (tid < B_) qd[tid] = qden[tid];
  __syncthreads();
  const int count = countp[0];
  const int r = blockIdx.x * 4 + wid;
  const float4 m4 = *(const float4*)(mem + (size_t)r * D_ + lane * 4);
  float sq = m4.x * m4.x + m4.y * m4.y + m4.z * m4.z + m4.w * m4.w;
  sq = wave_sum(sq);
  const float rn = sqrtf(sq) + 1e-8f;
  if (r < count) {
    for (int b = 0; b < B_; b++) {
      const float4 c4 = *(const float4*)&cls[b * D_ + lane * 4];
      float dt = m4.x * c4.x + m4.y * c4.y + m4.z * c4.z + m4.w * c4.w;
      dt = wave_sum(dt);
      if (lane == 0) sims[b * M_ + r] = dt / (qd[b] * rn);
    }
  } else if (lane == 0) {
    for (int b = 0; b < B_; b++) sims[b * M_ + r] = -1e9f;
  }
}

// ---------------- per-batch: top-4, softmax mix, classifier -----------------
__global__ __launch_bounds__(256) void topk_mix(const float* __restrict__ h,
                                                const float* __restrict__ mem,
                                                const float* __restrict__ simsg,
                                                const int* __restrict__ countp,
                                                const float* __restrict__ Wc,
                                                const float* __restrict__ bc,
                                                float* __restrict__ out) {
  __shared__ float sims[M_];
  __shared__ float cls[D_];
  __shared__ float rv[256];
  __shared__ int   ri[256];
  __shared__ float aug[D_];
  __shared__ float tv[4];
  __shared__ int   tix[4];

  const int b = blockIdx.x, tid = threadIdx.x;
  const int lane = tid & 63, wid = tid >> 6;
  const int count = countp[0];

  for (int i = tid; i < M_; i += 256) sims[i] = simsg[b * M_ + i];
  cls[tid] = h[(size_t)b * S_ * D_ + tid];
  __syncthreads();

  for (int k = 0; k < 4; k++) {
    float bv = -INFINITY; int bi = 1 << 30;
    for (int r = tid; r < M_; r += 256) {
      const float v = sims[r];
      if (v > bv || (v == bv && r < bi)) { bv = v; bi = r; }
    }
    rv[tid] = bv; ri[tid] = bi;
    __syncthreads();
    if (tid == 0) {
      float bb = rv[0]; int bbi = ri[0];
      for (int i = 1; i < 256; i++)
        if (rv[i] > bb || (rv[i] == bb && ri[i] < bbi)) { bb = rv[i]; bbi = ri[i]; }
      tv[k] = bb; tix[k] = bbi; sims[bbi] = -INFINITY;
    }
    __syncthreads();
  }

  float w[4];
  {
    const float mx = tv[0];
    float ws = 0.f;
#pragma unroll
    for (int k = 0; k < 4; k++) { w[k] = expf(tv[k] - mx); ws += w[k]; }
    const float inv = 1.f / ws;
#pragma unroll
    for (int k = 0; k < 4; k++) w[k] *= inv;
  }

  {
    float mv = 0.f;
    if (count > 0) {
#pragma unroll
      for (int k = 0; k < 4; k++) mv = fmaf(w[k], mem[(size_t)tix[k] * D_ + tid], mv);
    }
    aug[tid] = cls[tid] + mv;
  }
  __syncthreads();

  const float4 a4 = *(const float4*)&aug[lane * 4];
  for (int c = wid; c < NC_; c += 4) {
    const float4 wc = *(const float4*)(Wc + (size_t)c * D_ + lane * 4);
    float dt = a4.x * wc.x + a4.y * wc.y + a4.z * wc.z + a4.w * wc.w;
    dt = wave_sum(dt);
    if (lane == 0) out[b * NC_ + c] = dt + bc[c];
  }
}

// ---------------- launcher ---------------------------------------------------
extern "C" void kernel_launch(void* const* d_in, const int* in_sizes, int n_in,
                              void* d_out, int out_size, void* d_ws, size_t ws_size,
                              hipStream_t stream) {
  const int*   ids  = (const int*)d_in[0];
  const float* tok  = (const float*)d_in[1];
  const float* pos  = (const float*)d_in[2];
  const float* Wqkv = (const float*)d_in[3];
  const float* bqkv = (const float*)d_in[4];
  const float* Wo   = (const float*)d_in[5];
  const float* bo   = (const float*)d_in[6];
  const float* ln1g = (const float*)d_in[7];
  const float* ln1b = (const float*)d_in[8];
  const float* W1   = (const float*)d_in[9];
  const float* b1   = (const float*)d_in[10];
  const float* W2   = (const float*)d_in[11];
  const float* b2   = (const float*)d_in[12];
  const float* ln2g = (const float*)d_in[13];
  const float* ln2b = (const float*)d_in[14];
  const float* Wg1  = (const float*)d_in[15];
  const float* bg1  = (const float*)d_in[16];
  const float* Wg2  = (const float*)d_in[17];
  const float* bg2  = (const float*)d_in[18];
  const float* Wc   = (const float*)d_in[19];
  const float* bc   = (const float*)d_in[20];
  float* out = (float*)d_out;

  float* xA   = (float*)d_ws;
  float* xB   = xA  + (size_t)ROWS * D_;
  float* ob   = xB  + (size_t)ROWS * D_;
  float* pb   = ob  + (size_t)ROWS * D_;
  float* big  = pb  + (size_t)ROWS * D_;
  float* mem  = big + (size_t)ROWS * FF_;
  float* qden = mem + (size_t)M_ * D_;
  float* sims = qden + 64;
  int*   mask = (int*)(sims + (size_t)B_ * M_);
  int*   slots = mask + ROWS;
  int*   cnt   = slots + ROWS;

  emb_kernel<<<ROWS / 4, 256, 0, stream>>>(ids, tok, pos, xA);

  for (int l = 0; l < L_; l++) {
    gemm_bt<0><<<dim3(768 / 128, ROWS / 128), 512, 0, stream>>>(
        xA, Wqkv + (size_t)l * 768 * 256, bqkv + l * 768, big, ROWS, 768, 256);
    attn_kernel<<<B_ * H_, 1024, 0, stream>>>(big, ob);
    gemm_bt<0><<<dim3(256 / 128, ROWS / 128), 512, 0, stream>>>(
        ob, Wo + (size_t)l * 256 * 256, bo + l * 256, pb, ROWS, 256, 256);
    add_ln<<<ROWS / 4, 256, 0, stream>>>(xA, pb, ln1g + l * 256, ln1b + l * 256, xB);
    gemm_bt<1><<<dim3(1024 / 128, ROWS / 128), 512, 0, stream>>>(
        xB, W1 + (size_t)l * 1024 * 256, b1 + l * 1024, big, ROWS, 1024, 256);
    gemm_bt<0><<<dim3(256 / 128, ROWS / 128), 512, 0, stream>>>(
        big, W2 + (size_t)l * 256 * 1024, b2 + l * 256, pb, ROWS, 256, 1024);
    add_ln<<<ROWS / 4, 256, 0, stream>>>(xB, pb, ln2g + l * 256, ln2b + l * 256, xA);
  }

  // gate MLP: t = relu(h @ Wg1^T + bg1)  -> mask
  gemm_bt<1><<<dim3(256 / 128, ROWS / 128), 512, 0, stream>>>(
      xA, Wg1, bg1, ob, ROWS, 256, 256);
  gate_mask<<<ROWS / 4, 256, 0, stream>>>(ob, Wg2, bg2, mask);
  scan_kernel<<<1, 256, 0, stream>>>(mask, slots, cnt);
  (void)hipMemsetAsync(mem, 0, (size_t)M_ * D_ * sizeof(float), stream);
  scatter_kernel<<<ROWS / 4, 256, 0, stream>>>(xA, slots, mem);

  qnorm_kernel<<<B_ / 4, 256, 0, stream>>>(xA, qden);
  sims_kernel<<<M_ / 4, 256, 0, stream>>>(xA, mem, qden, cnt, sims);
  topk_mix<<<B_, 256, 0, stream>>>(xA, mem, sims, cnt, Wc, bc, out);
}

// Round 4
// 857.434 us; speedup vs baseline: 2.7584x; 1.5598x over previous
//
#include <hip/hip_runtime.h>
#include <math.h>

#define D_   256
#define H_   8
#define L_   2
#define FF_  1024
#define S_   512
#define B_   32
#define M_   4096
#define NC_  10
#define ROWS (B_*S_)   // 16384

typedef __attribute__((ext_vector_type(8))) short bf16x8;
typedef __attribute__((ext_vector_type(4))) float f32x4;

__device__ __forceinline__ float wave_sum(float v) {
#pragma unroll
  for (int off = 1; off < 64; off <<= 1) v += __shfl_xor(v, off, 64);
  return v;
}

__device__ __forceinline__ unsigned short bf16_rne(float x) {
  unsigned int b = __float_as_uint(x);
  return (unsigned short)((b + 0x7FFFu + ((b >> 16) & 1u)) >> 16);
}
__device__ __forceinline__ float bf16_f(unsigned short h) {
  return __uint_as_float(((unsigned int)h) << 16);
}

// convert float4 -> hi/lo bf16 quads, store 8B each into padded LDS tiles
__device__ __forceinline__ void cvt_store(unsigned short* Hq, unsigned short* Lq,
                                          int off, float4 v) {
  float f[4] = {v.x, v.y, v.z, v.w};
  unsigned short h[4], l[4];
#pragma unroll
  for (int i = 0; i < 4; i++) {
    h[i] = bf16_rne(f[i]);
    l[i] = bf16_rne(f[i] - bf16_f(h[i]));
  }
  uint2 hp, lp;
  hp.x = (unsigned int)h[0] | ((unsigned int)h[1] << 16);
  hp.y = (unsigned int)h[2] | ((unsigned int)h[3] << 16);
  lp.x = (unsigned int)l[0] | ((unsigned int)l[1] << 16);
  lp.y = (unsigned int)l[2] | ((unsigned int)l[3] << 16);
  *(uint2*)&Hq[off] = hp;
  *(uint2*)&Lq[off] = lp;
}

// ---------------- embedding ----------------
__global__ __launch_bounds__(256) void emb_kernel(const int* __restrict__ ids,
                                                  const float* __restrict__ tok,
                                                  const float* __restrict__ pos,
                                                  float* __restrict__ x) {
  const int row  = blockIdx.x * 4 + (threadIdx.x >> 6);
  const int lane = threadIdx.x & 63;
  const int id = ids[row];
  const int s  = row & (S_ - 1);
  const float4 t = *(const float4*)(tok + (size_t)id * D_ + lane * 4);
  const float4 p = *(const float4*)(pos + (size_t)s  * D_ + lane * 4);
  float4 r; r.x = t.x + p.x; r.y = t.y + p.y; r.z = t.z + p.z; r.w = t.w + p.w;
  *(float4*)(x + (size_t)row * D_ + lane * 4) = r;
}

// ---- split-bf16 MFMA GEMM: C[M,N] = A[M,K]*W[N,K]^T + bias (+ReLU) --------
// A,W fp32; each element split hi+lo (bf16); 3-term MFMA (hh, hl, lh).
// Tile BM x 128, BK=32, 512 threads (8 waves).
#define LPITCH 40  // bf16 elements per LDS row (32 data + 8 pad => 80B, 2-way free)
template<int BM, int RELU>
__global__ __launch_bounds__(512, 4) void gemm_mfma(const float* __restrict__ A,
                                                    const float* __restrict__ Bm,
                                                    const float* __restrict__ bias,
                                                    float* __restrict__ C,
                                                    int M, int N, int K) {
  constexpr int WGM = BM / 64;       // waves along M (2 or 1)
  constexpr int WGN = 8 / WGM;       // waves along N (4 or 8)
  constexpr int WN  = 128 / WGN;     // cols per wave (32 or 16)
  constexpr int FN  = WN / 16;       // n-frags per wave (2 or 1)
  __shared__ unsigned short Ah[BM * LPITCH];
  __shared__ unsigned short Al[BM * LPITCH];
  __shared__ unsigned short Bh[128 * LPITCH];
  __shared__ unsigned short Bl[128 * LPITCH];

  const int tid  = threadIdx.x;
  const int lane = tid & 63;
  const int wid  = tid >> 6;
  const int wm = wid / WGN, wn = wid % WGN;
  const int m0 = blockIdx.y * BM, n0 = blockIdx.x * 128;
  const int lrow  = lane & 15;
  const int khalf = (lane >> 4) * 8;     // bf16 element offset within row

  f32x4 acc[4][FN];
#pragma unroll
  for (int i = 0; i < 4; i++)
#pragma unroll
    for (int j = 0; j < FN; j++) acc[i][j] = (f32x4){0.f, 0.f, 0.f, 0.f};

  const float* Abase = A + (size_t)m0 * K;
  const float* Bbase = Bm + (size_t)n0 * K;

  for (int k0 = 0; k0 < K; k0 += 32) {
    __syncthreads();
    // stage A tile (BM x 32)
#pragma unroll
    for (int j = 0; j < BM / 64; j++) {
      const int idx = tid + j * 512;
      const int row = idx >> 3, kq = (idx & 7) << 2;
      const float4 v = *(const float4*)(Abase + (size_t)row * K + k0 + kq);
      cvt_store(Ah, Al, row * LPITCH + kq, v);
    }
    // stage B tile (128 x 32)
#pragma unroll
    for (int j = 0; j < 2; j++) {
      const int idx = tid + j * 512;
      const int row = idx >> 3, kq = (idx & 7) << 2;
      const float4 v = *(const float4*)(Bbase + (size_t)row * K + k0 + kq);
      cvt_store(Bh, Bl, row * LPITCH + kq, v);
    }
    __syncthreads();

    bf16x8 ah[4], al[4], bh[FN], bl[FN];
#pragma unroll
    for (int fm = 0; fm < 4; fm++) {
      const int r = (wm * 64 + fm * 16 + lrow) * LPITCH + khalf;
      ah[fm] = *(const bf16x8*)&Ah[r];
      al[fm] = *(const bf16x8*)&Al[r];
    }
#pragma unroll
    for (int fn = 0; fn < FN; fn++) {
      const int r = (wn * WN + fn * 16 + lrow) * LPITCH + khalf;
      bh[fn] = *(const bf16x8*)&Bh[r];
      bl[fn] = *(const bf16x8*)&Bl[r];
    }
#pragma unroll
    for (int fm = 0; fm < 4; fm++)
#pragma unroll
      for (int fn = 0; fn < FN; fn++) {
        acc[fm][fn] = __builtin_amdgcn_mfma_f32_16x16x32_bf16(ah[fm], bh[fn], acc[fm][fn], 0, 0, 0);
        acc[fm][fn] = __builtin_amdgcn_mfma_f32_16x16x32_bf16(ah[fm], bl[fn], acc[fm][fn], 0, 0, 0);
        acc[fm][fn] = __builtin_amdgcn_mfma_f32_16x16x32_bf16(al[fm], bh[fn], acc[fm][fn], 0, 0, 0);
      }
  }

  // epilogue: C/D mapping col=lane&15, row=(lane>>4)*4+reg
#pragma unroll
  for (int fm = 0; fm < 4; fm++)
#pragma unroll
    for (int fn = 0; fn < FN; fn++) {
      const int mrow = m0 + wm * 64 + fm * 16 + (lane >> 4) * 4;
      const int ncol = n0 + wn * WN + fn * 16 + (lane & 15);
      const float bi = bias[ncol];
#pragma unroll
      for (int r = 0; r < 4; r++) {
        float v = acc[fm][fn][r] + bi;
        if (RELU) v = fmaxf(v, 0.f);
        C[(size_t)(mrow + r) * N + ncol] = v;
      }
    }
}

// ---------------- attention: block per (b,h), 1024 threads ------------------
#define SCH 8
__global__ __launch_bounds__(1024, 4) void attn_kernel(const float* __restrict__ qkv,
                                                       float* __restrict__ o) {
  __shared__ float smem[8192];           // 32 KB
  float* Ks = smem;                      // [half][64][32]
  float* Vs = smem + 4096;               // [half][64][32]
  const int bh = blockIdx.x;
  const int b = bh >> 3, h = bh & 7;
  const int tid = threadIdx.x;
  const int half = tid >> 9;
  const int q = tid & 511;
  const float* base = qkv + (size_t)b * (S_ * 768);

  float qr[32];
  {
    const float* qp = base + (size_t)q * 768 + h * 32;
#pragma unroll
    for (int i = 0; i < 8; i++) *(float4*)&qr[i * 4] = *(const float4*)(qp + i * 4);
  }
  float m = -INFINITY, l = 0.f;
  float acc[32];
#pragma unroll
  for (int d = 0; d < 32; d++) acc[d] = 0.f;
  const float scale = 0.17677669529663687f;  // 1/sqrt(32)

  for (int t = 0; t < 4; t++) {
    __syncthreads();
#pragma unroll
    for (int jj = 0; jj < 2; jj++) {
      const int j  = tid + jj * 1024;
      const int hf = j >> 10;
      const int kv = (j >> 9) & 1;
      const int r  = (j >> 3) & 63;
      const int c4 = (j & 7) << 2;
      const float* src = base + (size_t)(hf * 256 + t * 64 + r) * 768 + 256 + kv * 256 + h * 32 + c4;
      float* dst = (kv ? Vs : Ks) + hf * 2048 + r * 32 + c4;
      *(float4*)dst = *(const float4*)src;
    }
    __syncthreads();
    const float* Kh = Ks + half * 2048;
    const float* Vh = Vs + half * 2048;
    for (int c0 = 0; c0 < 64; c0 += SCH) {
      float s[SCH];
#pragma unroll
      for (int j = 0; j < SCH; j++) {
        const float* kp = Kh + (c0 + j) * 32;
        float p0 = 0.f, p1 = 0.f, p2 = 0.f, p3 = 0.f;
#pragma unroll
        for (int d = 0; d < 32; d += 4) {
          p0 = fmaf(qr[d + 0], kp[d + 0], p0);
          p1 = fmaf(qr[d + 1], kp[d + 1], p1);
          p2 = fmaf(qr[d + 2], kp[d + 2], p2);
          p3 = fmaf(qr[d + 3], kp[d + 3], p3);
        }
        s[j] = ((p0 + p1) + (p2 + p3)) * scale;
      }
      float cm = s[0];
#pragma unroll
      for (int j = 1; j < SCH; j++) cm = fmaxf(cm, s[j]);
      const float mn = fmaxf(m, cm);
      const float corr = __expf(m - mn);
      m = mn;
      l *= corr;
#pragma unroll
      for (int d = 0; d < 32; d++) acc[d] *= corr;
#pragma unroll
      for (int j = 0; j < SCH; j++) {
        const float p = __expf(s[j] - mn);
        l += p;
        const float* vp = Vh + (c0 + j) * 32;
#pragma unroll
        for (int d = 0; d < 32; d++) acc[d] = fmaf(p, vp[d], acc[d]);
      }
    }
  }

  // ---- merge the two halves ----
  __syncthreads();
  smem[tid * 2] = m; smem[tid * 2 + 1] = l;
  __syncthreads();
  const int partner = tid ^ 512;
  const float m2 = smem[partner * 2], l2 = smem[partner * 2 + 1];
  const float ms = fmaxf(m, m2);
  const float a1 = __expf(m - ms);
  const float a2 = __expf(m2 - ms);
  const float lt = l * a1 + l2 * a2;
  __syncthreads();

  float* op = o + (size_t)(b * S_ + q) * D_ + h * 32;
  const float inv = 1.f / lt;
  float* ab = smem;
#pragma unroll
  for (int ph = 0; ph < 2; ph++) {
    if (half == 1) {
#pragma unroll
      for (int d4 = 0; d4 < 16; d4 += 4)
        *(float4*)&ab[q * 16 + d4] = *(const float4*)&acc[ph * 16 + d4];
    }
    __syncthreads();
    if (half == 0) {
#pragma unroll
      for (int d4 = 0; d4 < 16; d4 += 4) {
        const float4 pv = *(const float4*)&ab[q * 16 + d4];
        float4 r;
        r.x = (acc[ph * 16 + d4 + 0] * a1 + pv.x * a2) * inv;
        r.y = (acc[ph * 16 + d4 + 1] * a1 + pv.y * a2) * inv;
        r.z = (acc[ph * 16 + d4 + 2] * a1 + pv.z * a2) * inv;
        r.w = (acc[ph * 16 + d4 + 3] * a1 + pv.w * a2) * inv;
        *(float4*)(op + ph * 16 + d4) = r;
      }
    }
    __syncthreads();
  }
}

// ---------------- fused residual + layernorm (one wave per row) -------------
__global__ __launch_bounds__(256) void add_ln(const float* __restrict__ x,
                                              const float* __restrict__ y,
                                              const float* __restrict__ g,
                                              const float* __restrict__ bta,
                                              float* __restrict__ out) {
  const int row  = blockIdx.x * 4 + (threadIdx.x >> 6);
  const int lane = threadIdx.x & 63;
  const size_t base = (size_t)row * D_ + lane * 4;
  const float4 xv = *(const float4*)(x + base);
  const float4 yv = *(const float4*)(y + base);
  float v[4] = {xv.x + yv.x, xv.y + yv.y, xv.z + yv.z, xv.w + yv.w};
  float s = v[0] + v[1] + v[2] + v[3];
  s = wave_sum(s);
  const float mean = s * (1.f / 256.f);
  float d[4] = {v[0] - mean, v[1] - mean, v[2] - mean, v[3] - mean};
  float sq = d[0] * d[0] + d[1] * d[1] + d[2] * d[2] + d[3] * d[3];
  sq = wave_sum(sq);
  const float inv = 1.f / sqrtf(sq * (1.f / 256.f) + 1e-5f);
  const float4 gv = *(const float4*)(g + lane * 4);
  const float4 bv = *(const float4*)(bta + lane * 4);
  float4 r;
  r.x = d[0] * inv * gv.x + bv.x; r.y = d[1] * inv * gv.y + bv.y;
  r.z = d[2] * inv * gv.z + bv.z; r.w = d[3] * inv * gv.w + bv.w;
  *(float4*)(out + base) = r;
}

// ---------------- gate logit -> mask ----------------------------------------
__global__ __launch_bounds__(256) void gate_mask(const float* __restrict__ t,
                                                 const float* __restrict__ Wg2,
                                                 const float* __restrict__ bg2,
                                                 int* __restrict__ mask) {
  const int row  = blockIdx.x * 4 + (threadIdx.x >> 6);
  const int lane = threadIdx.x & 63;
  const float4 tv = *(const float4*)(t + (size_t)row * D_ + lane * 4);
  const float4 wv = *(const float4*)(Wg2 + lane * 4);
  float s = tv.x * wv.x + tv.y * wv.y + tv.z * wv.z + tv.w * wv.w;
  s = wave_sum(s);
  if (lane == 0) mask[row] = (s + bg2[0]) > 0.f ? 1 : 0;
}

// ---------------- sequential prefix-scan over 16384 masks -------------------
__global__ __launch_bounds__(256) void scan_kernel(const int* __restrict__ mask,
                                                   int* __restrict__ slots,
                                                   int* __restrict__ countp) {
  __shared__ int ps[256];
  const int tid = threadIdx.x;
  const int base = tid * 64;
  int s = 0;
  for (int i = 0; i < 64; i++) s += mask[base + i];
  ps[tid] = s;
  __syncthreads();
  if (tid == 0) {
    int run = 0;
    for (int i = 0; i < 256; i++) { const int t = ps[i]; ps[i] = run; run += t; }
    countp[0] = run < M_ ? run : M_;
  }
  __syncthreads();
  int run = ps[tid];
  for (int i = 0; i < 64; i++) {
    const int r = base + i;
    const int mk = mask[r];
    slots[r] = (mk && run < M_) ? run : -1;
    run += mk;
  }
}

// ---------------- scatter selected rows into memory -------------------------
__global__ __launch_bounds__(256) void scatter_kernel(const float* __restrict__ h,
                                                      const int* __restrict__ slots,
                                                      float* __restrict__ mem) {
  const int row  = blockIdx.x * 4 + (threadIdx.x >> 6);
  const int lane = threadIdx.x & 63;
  const int sl = slots[row];
  if (sl >= 0)
    *(float4*)(mem + (size_t)sl * D_ + lane * 4) =
        *(const float4*)(h + (size_t)row * D_ + lane * 4);
}

// ---------------- query norms (one wave per batch row) ----------------------
__global__ __launch_bounds__(256) void qnorm_kernel(const float* __restrict__ h,
                                                    float* __restrict__ qden) {
  const int b    = blockIdx.x * 4 + (threadIdx.x >> 6);
  const int lane = threadIdx.x & 63;
  const float4 c = *(const float4*)(h + (size_t)b * S_ * D_ + lane * 4);
  float sq = c.x * c.x + c.y * c.y + c.z * c.z + c.w * c.w;
  sq = wave_sum(sq);
  if (lane == 0) qden[b] = sqrtf(sq) + 1e-8f;
}

// ------- sims[b][r] for all 32 b: one wave per memory row r -----------------
__global__ __launch_bounds__(256) void sims_kernel(const float* __restrict__ h,
                                                   const float* __restrict__ mem,
                                                   const float* __restrict__ qden,
                                                   const int* __restrict__ countp,
                                                   float* __restrict__ sims) {
  __shared__ float cls[B_ * D_];
  __shared__ float qd[B_];
  const int tid = threadIdx.x;
  const int lane = tid & 63, wid = tid >> 6;
  for (int i = tid; i < B_ * D_ / 4; i += 256) {
    const int flat = i * 4;
    const int b = flat >> 8, d = flat & 255;
    *(float4*)&cls[flat] = *(const float4*)(h + (size_t)b * S_ * D_ + d);
  }
  if (tid < B_) qd[tid] = qden[tid];
  __syncthreads();
  const int count = countp[0];
  const int r = blockIdx.x * 4 + wid;
  const float4 m4 = *(const float4*)(mem + (size_t)r * D_ + lane * 4);
  float sq = m4.x * m4.x + m4.y * m4.y + m4.z * m4.z + m4.w * m4.w;
  sq = wave_sum(sq);
  const float rn = sqrtf(sq) + 1e-8f;
  if (r < count) {
    for (int b = 0; b < B_; b++) {
      const float4 c4 = *(const float4*)&cls[b * D_ + lane * 4];
      float dt = m4.x * c4.x + m4.y * c4.y + m4.z * c4.z + m4.w * c4.w;
      dt = wave_sum(dt);
      if (lane == 0) sims[b * M_ + r] = dt / (qd[b] * rn);
    }
  } else if (lane == 0) {
    for (int b = 0; b < B_; b++) sims[b * M_ + r] = -1e9f;
  }
}

// ---------------- per-batch: top-4, softmax mix, classifier -----------------
__global__ __launch_bounds__(256) void topk_mix(const float* __restrict__ h,
                                                const float* __restrict__ mem,
                                                const float* __restrict__ simsg,
                                                const int* __restrict__ countp,
                                                const float* __restrict__ Wc,
                                                const float* __restrict__ bc,
                                                float* __restrict__ out) {
  __shared__ float sims[M_];
  __shared__ float cls[D_];
  __shared__ float rv[256];
  __shared__ int   ri[256];
  __shared__ float aug[D_];
  __shared__ float tv[4];
  __shared__ int   tix[4];

  const int b = blockIdx.x, tid = threadIdx.x;
  const int lane = tid & 63, wid = tid >> 6;
  const int count = countp[0];

  for (int i = tid; i < M_; i += 256) sims[i] = simsg[b * M_ + i];
  cls[tid] = h[(size_t)b * S_ * D_ + tid];
  __syncthreads();

  for (int k = 0; k < 4; k++) {
    float bv = -INFINITY; int bi = 1 << 30;
    for (int r = tid; r < M_; r += 256) {
      const float v = sims[r];
      if (v > bv || (v == bv && r < bi)) { bv = v; bi = r; }
    }
    rv[tid] = bv; ri[tid] = bi;
    __syncthreads();
    if (tid == 0) {
      float bb = rv[0]; int bbi = ri[0];
      for (int i = 1; i < 256; i++)
        if (rv[i] > bb || (rv[i] == bb && ri[i] < bbi)) { bb = rv[i]; bbi = ri[i]; }
      tv[k] = bb; tix[k] = bbi; sims[bbi] = -INFINITY;
    }
    __syncthreads();
  }

  float w[4];
  {
    const float mx = tv[0];
    float ws = 0.f;
#pragma unroll
    for (int k = 0; k < 4; k++) { w[k] = expf(tv[k] - mx); ws += w[k]; }
    const float inv = 1.f / ws;
#pragma unroll
    for (int k = 0; k < 4; k++) w[k] *= inv;
  }

  {
    float mv = 0.f;
    if (count > 0) {
#pragma unroll
      for (int k = 0; k < 4; k++) mv = fmaf(w[k], mem[(size_t)tix[k] * D_ + tid], mv);
    }
    aug[tid] = cls[tid] + mv;
  }
  __syncthreads();

  const float4 a4 = *(const float4*)&aug[lane * 4];
  for (int c = wid; c < NC_; c += 4) {
    const float4 wc = *(const float4*)(Wc + (size_t)c * D_ + lane * 4);
    float dt = a4.x * wc.x + a4.y * wc.y + a4.z * wc.z + a4.w * wc.w;
    dt = wave_sum(dt);
    if (lane == 0) out[b * NC_ + c] = dt + bc[c];
  }
}

// ---------------- launcher ---------------------------------------------------
extern "C" void kernel_launch(void* const* d_in, const int* in_sizes, int n_in,
                              void* d_out, int out_size, void* d_ws, size_t ws_size,
                              hipStream_t stream) {
  const int*   ids  = (const int*)d_in[0];
  const float* tok  = (const float*)d_in[1];
  const float* pos  = (const float*)d_in[2];
  const float* Wqkv = (const float*)d_in[3];
  const float* bqkv = (const float*)d_in[4];
  const float* Wo   = (const float*)d_in[5];
  const float* bo   = (const float*)d_in[6];
  const float* ln1g = (const float*)d_in[7];
  const float* ln1b = (const float*)d_in[8];
  const float* W1   = (const float*)d_in[9];
  const float* b1   = (const float*)d_in[10];
  const float* W2   = (const float*)d_in[11];
  const float* b2   = (const float*)d_in[12];
  const float* ln2g = (const float*)d_in[13];
  const float* ln2b = (const float*)d_in[14];
  const float* Wg1  = (const float*)d_in[15];
  const float* bg1  = (const float*)d_in[16];
  const float* Wg2  = (const float*)d_in[17];
  const float* bg2  = (const float*)d_in[18];
  const float* Wc   = (const float*)d_in[19];
  const float* bc   = (const float*)d_in[20];
  float* out = (float*)d_out;

  float* xA   = (float*)d_ws;
  float* xB   = xA  + (size_t)ROWS * D_;
  float* ob   = xB  + (size_t)ROWS * D_;
  float* pb   = ob  + (size_t)ROWS * D_;
  float* big  = pb  + (size_t)ROWS * D_;
  float* mem  = big + (size_t)ROWS * FF_;
  float* qden = mem + (size_t)M_ * D_;
  float* sims = qden + 64;
  int*   mask = (int*)(sims + (size_t)B_ * M_);
  int*   slots = mask + ROWS;
  int*   cnt   = slots + ROWS;

  emb_kernel<<<ROWS / 4, 256, 0, stream>>>(ids, tok, pos, xA);

  for (int l = 0; l < L_; l++) {
    gemm_mfma<128, 0><<<dim3(768 / 128, ROWS / 128), 512, 0, stream>>>(
        xA, Wqkv + (size_t)l * 768 * 256, bqkv + l * 768, big, ROWS, 768, 256);
    attn_kernel<<<B_ * H_, 1024, 0, stream>>>(big, ob);
    gemm_mfma<64, 0><<<dim3(256 / 128, ROWS / 64), 512, 0, stream>>>(
        ob, Wo + (size_t)l * 256 * 256, bo + l * 256, pb, ROWS, 256, 256);
    add_ln<<<ROWS / 4, 256, 0, stream>>>(xA, pb, ln1g + l * 256, ln1b + l * 256, xB);
    gemm_mfma<128, 1><<<dim3(1024 / 128, ROWS / 128), 512, 0, stream>>>(
        xB, W1 + (size_t)l * 1024 * 256, b1 + l * 1024, big, ROWS, 1024, 256);
    gemm_mfma<64, 0><<<dim3(256 / 128, ROWS / 64), 512, 0, stream>>>(
        big, W2 + (size_t)l * 256 * 1024, b2 + l * 256, pb, ROWS, 256, 1024);
    add_ln<<<ROWS / 4, 256, 0, stream>>>(xB, pb, ln2g + l * 256, ln2b + l * 256, xA);
  }

  // gate MLP: t = relu(h @ Wg1^T + bg1)  -> mask
  gemm_mfma<64, 1><<<dim3(256 / 128, ROWS / 64), 512, 0, stream>>>(
      xA, Wg1, bg1, ob, ROWS, 256, 256);
  gate_mask<<<ROWS / 4, 256, 0, stream>>>(ob, Wg2, bg2, mask);
  scan_kernel<<<1, 256, 0, stream>>>(mask, slots, cnt);
  (void)hipMemsetAsync(mem, 0, (size_t)M_ * D_ * sizeof(float), stream);
  scatter_kernel<<<ROWS / 4, 256, 0, stream>>>(xA, slots, mem);

  qnorm_kernel<<<B_ / 4, 256, 0, stream>>>(xA, qden);
  sims_kernel<<<M_ / 4, 256, 0, stream>>>(xA, mem, qden, cnt, sims);
  topk_mix<<<B_, 256, 0, stream>>>(xA, mem, sims, cnt, Wc, bc, out);
}

// Round 5
// 577.584 us; speedup vs baseline: 4.0949x; 1.4845x over previous
//
#include <hip/hip_runtime.h>
#include <math.h>

#define D_   256
#define H_   8
#define L_   2
#define FF_  1024
#define S_   512
#define B_   32
#define M_   4096
#define NC_  10
#define ROWS (B_*S_)   // 16384

typedef __attribute__((ext_vector_type(8))) short bf16x8;
typedef __attribute__((ext_vector_type(4))) float f32x4;

__device__ __forceinline__ float wave_sum(float v) {
#pragma unroll
  for (int off = 1; off < 64; off <<= 1) v += __shfl_xor(v, off, 64);
  return v;
}

__device__ __forceinline__ unsigned short bf16_rne(float x) {
  unsigned int b = __float_as_uint(x);
  return (unsigned short)((b + 0x7FFFu + ((b >> 16) & 1u)) >> 16);
}
__device__ __forceinline__ float bf16_f(unsigned short h) {
  return __uint_as_float(((unsigned int)h) << 16);
}
__device__ __forceinline__ unsigned int cvt_pk_bf16(float a, float b) {
  unsigned int r;
  asm volatile("v_cvt_pk_bf16_f32 %0, %1, %2" : "=v"(r) : "v"(a), "v"(b));
  return r;
}

// convert float4 -> hi/lo bf16 quads, store 8B each into padded LDS tiles
__device__ __forceinline__ void cvt_store(unsigned short* Hq, unsigned short* Lq,
                                          int off, float4 v) {
  float f[4] = {v.x, v.y, v.z, v.w};
  unsigned short h[4], l[4];
#pragma unroll
  for (int i = 0; i < 4; i++) {
    h[i] = bf16_rne(f[i]);
    l[i] = bf16_rne(f[i] - bf16_f(h[i]));
  }
  uint2 hp, lp;
  hp.x = (unsigned int)h[0] | ((unsigned int)h[1] << 16);
  hp.y = (unsigned int)h[2] | ((unsigned int)h[3] << 16);
  lp.x = (unsigned int)l[0] | ((unsigned int)l[1] << 16);
  lp.y = (unsigned int)l[2] | ((unsigned int)l[3] << 16);
  *(uint2*)&Hq[off] = hp;
  *(uint2*)&Lq[off] = lp;
}

// ---------------- embedding ----------------
__global__ __launch_bounds__(256) void emb_kernel(const int* __restrict__ ids,
                                                  const float* __restrict__ tok,
                                                  const float* __restrict__ pos,
                                                  float* __restrict__ x) {
  const int row  = blockIdx.x * 4 + (threadIdx.x >> 6);
  const int lane = threadIdx.x & 63;
  const int id = ids[row];
  const int s  = row & (S_ - 1);
  const float4 t = *(const float4*)(tok + (size_t)id * D_ + lane * 4);
  const float4 p = *(const float4*)(pos + (size_t)s  * D_ + lane * 4);
  float4 r; r.x = t.x + p.x; r.y = t.y + p.y; r.z = t.z + p.z; r.w = t.w + p.w;
  *(float4*)(x + (size_t)row * D_ + lane * 4) = r;
}

// ---- split-bf16 MFMA GEMM: C[M,N] = A[M,K]*W[N,K]^T + bias (+ReLU) --------
#define LPITCH 40
template<int BM, int RELU>
__global__ __launch_bounds__(512, 4) void gemm_mfma(const float* __restrict__ A,
                                                    const float* __restrict__ Bm,
                                                    const float* __restrict__ bias,
                                                    float* __restrict__ C,
                                                    int M, int N, int K) {
  constexpr int WGM = BM / 64;
  constexpr int WGN = 8 / WGM;
  constexpr int WN  = 128 / WGN;
  constexpr int FN  = WN / 16;
  __shared__ unsigned short Ah[BM * LPITCH];
  __shared__ unsigned short Al[BM * LPITCH];
  __shared__ unsigned short Bh[128 * LPITCH];
  __shared__ unsigned short Bl[128 * LPITCH];

  const int tid  = threadIdx.x;
  const int lane = tid & 63;
  const int wid  = tid >> 6;
  const int wm = wid / WGN, wn = wid % WGN;
  const int m0 = blockIdx.y * BM, n0 = blockIdx.x * 128;
  const int lrow  = lane & 15;
  const int khalf = (lane >> 4) * 8;

  f32x4 acc[4][FN];
#pragma unroll
  for (int i = 0; i < 4; i++)
#pragma unroll
    for (int j = 0; j < FN; j++) acc[i][j] = (f32x4){0.f, 0.f, 0.f, 0.f};

  const float* Abase = A + (size_t)m0 * K;
  const float* Bbase = Bm + (size_t)n0 * K;

  for (int k0 = 0; k0 < K; k0 += 32) {
    __syncthreads();
#pragma unroll
    for (int j = 0; j < BM / 64; j++) {
      const int idx = tid + j * 512;
      const int row = idx >> 3, kq = (idx & 7) << 2;
      const float4 v = *(const float4*)(Abase + (size_t)row * K + k0 + kq);
      cvt_store(Ah, Al, row * LPITCH + kq, v);
    }
#pragma unroll
    for (int j = 0; j < 2; j++) {
      const int idx = tid + j * 512;
      const int row = idx >> 3, kq = (idx & 7) << 2;
      const float4 v = *(const float4*)(Bbase + (size_t)row * K + k0 + kq);
      cvt_store(Bh, Bl, row * LPITCH + kq, v);
    }
    __syncthreads();

    bf16x8 ah[4], al[4], bh[FN], bl[FN];
#pragma unroll
    for (int fm = 0; fm < 4; fm++) {
      const int r = (wm * 64 + fm * 16 + lrow) * LPITCH + khalf;
      ah[fm] = *(const bf16x8*)&Ah[r];
      al[fm] = *(const bf16x8*)&Al[r];
    }
#pragma unroll
    for (int fn = 0; fn < FN; fn++) {
      const int r = (wn * WN + fn * 16 + lrow) * LPITCH + khalf;
      bh[fn] = *(const bf16x8*)&Bh[r];
      bl[fn] = *(const bf16x8*)&Bl[r];
    }
#pragma unroll
    for (int fm = 0; fm < 4; fm++)
#pragma unroll
      for (int fn = 0; fn < FN; fn++) {
        acc[fm][fn] = __builtin_amdgcn_mfma_f32_16x16x32_bf16(ah[fm], bh[fn], acc[fm][fn], 0, 0, 0);
        acc[fm][fn] = __builtin_amdgcn_mfma_f32_16x16x32_bf16(ah[fm], bl[fn], acc[fm][fn], 0, 0, 0);
        acc[fm][fn] = __builtin_amdgcn_mfma_f32_16x16x32_bf16(al[fm], bh[fn], acc[fm][fn], 0, 0, 0);
      }
  }

#pragma unroll
  for (int fm = 0; fm < 4; fm++)
#pragma unroll
    for (int fn = 0; fn < FN; fn++) {
      const int mrow = m0 + wm * 64 + fm * 16 + (lane >> 4) * 4;
      const int ncol = n0 + wn * WN + fn * 16 + (lane & 15);
      const float bi = bias[ncol];
#pragma unroll
      for (int r = 0; r < 4; r++) {
        float v = acc[fm][fn][r] + bi;
        if (RELU) v = fmaxf(v, 0.f);
        C[(size_t)(mrow + r) * N + ncol] = v;
      }
    }
}

// ---------------- MFMA attention -------------------------------------------
// Block = (b,h), 512 threads (8 waves x 64 q rows). Whole K (hi/lo) and V^T
// (hi/lo) staged in LDS once. No-max softmax (scores bounded): p = exp(s),
// l = sum p, O = (P*V)/l. QK^T computed swapped: S^T = mfma(A=K, B=Q) so a
// lane holds consecutive k's in registers for one q; P^T B-frags for
// O^T = mfma(A=V^T, B=P^T) built via register packs + ds_bpermute.
#define KPITCH 40   // u16 per K row   (80B, 16B aligned, 2-way-free b128 reads)
#define VPITCH 520  // u16 per Vt row  (1040B, 16B aligned, 2-way-free)
__global__ __launch_bounds__(512, 2) void attn_mfma(const float* __restrict__ qkv,
                                                    float* __restrict__ o) {
  __shared__ unsigned short Kh[512 * KPITCH];
  __shared__ unsigned short Kl[512 * KPITCH];
  __shared__ unsigned short Vth[32 * VPITCH];
  __shared__ unsigned short Vtl[32 * VPITCH];

  const int bh = blockIdx.x;
  const int b = bh >> 3, h = bh & 7;
  const int tid = threadIdx.x;
  const int lane = tid & 63;
  const int wv = tid >> 6;
  const float* base = qkv + (size_t)b * (S_ * 768) + h * 32;

  // ---- stage: threads 0..255 -> V^T (2 rows each), 256..511 -> K (2 rows) --
  if (tid < 256) {
    float v0[32], v1[32];
    const float* p0 = base + (size_t)(2 * tid) * 768 + 512;
    const float* p1 = p0 + 768;
#pragma unroll
    for (int i = 0; i < 8; i++) {
      *(float4*)&v0[i * 4] = *(const float4*)(p0 + i * 4);
      *(float4*)&v1[i * 4] = *(const float4*)(p1 + i * 4);
    }
#pragma unroll
    for (int d = 0; d < 32; d++) {
      const unsigned short h0 = bf16_rne(v0[d]), h1 = bf16_rne(v1[d]);
      const unsigned short l0 = bf16_rne(v0[d] - bf16_f(h0));
      const unsigned short l1 = bf16_rne(v1[d] - bf16_f(h1));
      *(unsigned int*)&Vth[d * VPITCH + 2 * tid] = (unsigned int)h0 | ((unsigned int)h1 << 16);
      *(unsigned int*)&Vtl[d * VPITCH + 2 * tid] = (unsigned int)l0 | ((unsigned int)l1 << 16);
    }
  } else {
    const int t = tid - 256;
#pragma unroll
    for (int rr = 0; rr < 2; rr++) {
      const int k = 2 * t + rr;
      const float* p = base + (size_t)k * 768 + 256;
      float kv[32];
#pragma unroll
      for (int i = 0; i < 8; i++) *(float4*)&kv[i * 4] = *(const float4*)(p + i * 4);
#pragma unroll
      for (int d = 0; d < 32; d += 2) {
        const unsigned short h0 = bf16_rne(kv[d]), h1 = bf16_rne(kv[d + 1]);
        const unsigned short l0 = bf16_rne(kv[d] - bf16_f(h0));
        const unsigned short l1 = bf16_rne(kv[d + 1] - bf16_f(h1));
        *(unsigned int*)&Kh[k * KPITCH + d] = (unsigned int)h0 | ((unsigned int)h1 << 16);
        *(unsigned int*)&Kl[k * KPITCH + d] = (unsigned int)l0 | ((unsigned int)l1 << 16);
      }
    }
  }

  // ---- per-wave Q B-fragments (scale folded in), kept in registers --------
  const int q0 = wv * 64;
  bf16x8 qh[4], ql[4];
#pragma unroll
  for (int f = 0; f < 4; f++) {
    const float* qp = base + (size_t)(q0 + f * 16 + (lane & 15)) * 768 + ((lane >> 4) * 8);
    float qq[8];
    *(float4*)&qq[0] = *(const float4*)qp;
    *(float4*)&qq[4] = *(const float4*)(qp + 4);
    bf16x8 vh, vl;
#pragma unroll
    for (int j = 0; j < 8; j++) {
      const float sv = qq[j] * 0.17677669529663687f;
      const unsigned short hh = bf16_rne(sv);
      vh[j] = (short)hh;
      vl[j] = (short)bf16_rne(sv - bf16_f(hh));
    }
    qh[f] = vh; ql[f] = vl;
  }

  __syncthreads();

  f32x4 oacc[2][4];   // [d-frag][q-frag], O^T: row=d, col=q
#pragma unroll
  for (int i = 0; i < 2; i++)
#pragma unroll
    for (int j = 0; j < 4; j++) oacc[i][j] = (f32x4){0.f, 0.f, 0.f, 0.f};
  float lacc[4] = {0.f, 0.f, 0.f, 0.f};

  const int idx01 = (lane & 15) + ((lane & 16) << 1);  // +32 if bit4 set
  const int idx23 = idx01 + 16;
  const bool hiSel = (lane & 32) != 0;

  for (int kt = 0; kt < S_; kt += 32) {
    // K A-fragments (2 sub-tiles of 16 k)
    bf16x8 kah[2], kal[2];
#pragma unroll
    for (int u = 0; u < 2; u++) {
      const int off = (kt + u * 16 + (lane & 15)) * KPITCH + ((lane >> 4) * 8);
      kah[u] = *(const bf16x8*)&Kh[off];
      kal[u] = *(const bf16x8*)&Kl[off];
    }
    // V^T A-fragments (2 d-frags)
    bf16x8 vah[2], val[2];
#pragma unroll
    for (int df = 0; df < 2; df++) {
      const int off = (df * 16 + (lane & 15)) * VPITCH + kt + ((lane >> 4) * 8);
      vah[df] = *(const bf16x8*)&Vth[off];
      val[df] = *(const bf16x8*)&Vtl[off];
    }
    // S^T = K . Q^T  (3-term split)
    f32x4 s[2][4];
#pragma unroll
    for (int u = 0; u < 2; u++)
#pragma unroll
      for (int f = 0; f < 4; f++) {
        f32x4 a = (f32x4){0.f, 0.f, 0.f, 0.f};
        a = __builtin_amdgcn_mfma_f32_16x16x32_bf16(kal[u], qh[f], a, 0, 0, 0);
        a = __builtin_amdgcn_mfma_f32_16x16x32_bf16(kah[u], ql[f], a, 0, 0, 0);
        a = __builtin_amdgcn_mfma_f32_16x16x32_bf16(kah[u], qh[f], a, 0, 0, 0);
        s[u][f] = a;
      }
    // exp + hi/lo pack (k-pairs live in regs: lane holds k = 16u + 4g + r)
    unsigned int ah[2][4][2], alw[2][4][2];
#pragma unroll
    for (int u = 0; u < 2; u++)
#pragma unroll
      for (int f = 0; f < 4; f++) {
        const float p0 = __expf(s[u][f][0]);
        const float p1 = __expf(s[u][f][1]);
        const float p2 = __expf(s[u][f][2]);
        const float p3 = __expf(s[u][f][3]);
        lacc[f] += (p0 + p1) + (p2 + p3);
        const unsigned int h01 = cvt_pk_bf16(p0, p1);
        const unsigned int h23 = cvt_pk_bf16(p2, p3);
        const float r0 = p0 - __uint_as_float(h01 << 16);
        const float r1 = p1 - __uint_as_float(h01 & 0xffff0000u);
        const float r2 = p2 - __uint_as_float(h23 << 16);
        const float r3 = p3 - __uint_as_float(h23 & 0xffff0000u);
        ah[u][f][0] = h01; ah[u][f][1] = h23;
        alw[u][f][0] = cvt_pk_bf16(r0, r1);
        alw[u][f][1] = cvt_pk_bf16(r2, r3);
      }
    // per q-frag: build P^T B-frag via bpermute, then PV MFMAs
#pragma unroll
    for (int f = 0; f < 4; f++) {
      union { unsigned int w[4]; bf16x8 v; } ph, pl;
      {
        const unsigned int t0 = (unsigned int)__shfl((int)ah[0][f][0], idx01, 64);
        const unsigned int t1 = (unsigned int)__shfl((int)ah[1][f][0], idx01, 64);
        ph.w[0] = hiSel ? t1 : t0;
      }
      {
        const unsigned int t0 = (unsigned int)__shfl((int)ah[0][f][1], idx01, 64);
        const unsigned int t1 = (unsigned int)__shfl((int)ah[1][f][1], idx01, 64);
        ph.w[1] = hiSel ? t1 : t0;
      }
      {
        const unsigned int t0 = (unsigned int)__shfl((int)ah[0][f][0], idx23, 64);
        const unsigned int t1 = (unsigned int)__shfl((int)ah[1][f][0], idx23, 64);
        ph.w[2] = hiSel ? t1 : t0;
      }
      {
        const unsigned int t0 = (unsigned int)__shfl((int)ah[0][f][1], idx23, 64);
        const unsigned int t1 = (unsigned int)__shfl((int)ah[1][f][1], idx23, 64);
        ph.w[3] = hiSel ? t1 : t0;
      }
      {
        const unsigned int t0 = (unsigned int)__shfl((int)alw[0][f][0], idx01, 64);
        const unsigned int t1 = (unsigned int)__shfl((int)alw[1][f][0], idx01, 64);
        pl.w[0] = hiSel ? t1 : t0;
      }
      {
        const unsigned int t0 = (unsigned int)__shfl((int)alw[0][f][1], idx01, 64);
        const unsigned int t1 = (unsigned int)__shfl((int)alw[1][f][1], idx01, 64);
        pl.w[1] = hiSel ? t1 : t0;
      }
      {
        const unsigned int t0 = (unsigned int)__shfl((int)alw[0][f][0], idx23, 64);
        const unsigned int t1 = (unsigned int)__shfl((int)alw[1][f][0], idx23, 64);
        pl.w[2] = hiSel ? t1 : t0;
      }
      {
        const unsigned int t0 = (unsigned int)__shfl((int)alw[0][f][1], idx23, 64);
        const unsigned int t1 = (unsigned int)__shfl((int)alw[1][f][1], idx23, 64);
        pl.w[3] = hiSel ? t1 : t0;
      }
#pragma unroll
      for (int df = 0; df < 2; df++) {
        oacc[df][f] = __builtin_amdgcn_mfma_f32_16x16x32_bf16(val[df], ph.v, oacc[df][f], 0, 0, 0);
        oacc[df][f] = __builtin_amdgcn_mfma_f32_16x16x32_bf16(vah[df], pl.v, oacc[df][f], 0, 0, 0);
        oacc[df][f] = __builtin_amdgcn_mfma_f32_16x16x32_bf16(vah[df], ph.v, oacc[df][f], 0, 0, 0);
      }
    }
  }

  // reduce l across the 4 lane-groups (each held different k's)
#pragma unroll
  for (int f = 0; f < 4; f++) {
    lacc[f] += __shfl_xor(lacc[f], 16, 64);
    lacc[f] += __shfl_xor(lacc[f], 32, 64);
  }
  // store O: lane holds col q = lane&15 (q-frag f), rows d = df*16+(lane>>4)*4+r
#pragma unroll
  for (int f = 0; f < 4; f++) {
    const float inv = 1.f / lacc[f];
    const int q = q0 + f * 16 + (lane & 15);
    float* op = o + (size_t)(b * S_ + q) * D_ + h * 32;
#pragma unroll
    for (int df = 0; df < 2; df++) {
      const int dbase = df * 16 + (lane >> 4) * 4;
#pragma unroll
      for (int r = 0; r < 4; r++)
        op[dbase + r] = oacc[df][f][r] * inv;
    }
  }
}

// ---------------- fused residual + layernorm (one wave per row) -------------
__global__ __launch_bounds__(256) void add_ln(const float* __restrict__ x,
                                              const float* __restrict__ y,
                                              const float* __restrict__ g,
                                              const float* __restrict__ bta,
                                              float* __restrict__ out) {
  const int row  = blockIdx.x * 4 + (threadIdx.x >> 6);
  const int lane = threadIdx.x & 63;
  const size_t base = (size_t)row * D_ + lane * 4;
  const float4 xv = *(const float4*)(x + base);
  const float4 yv = *(const float4*)(y + base);
  float v[4] = {xv.x + yv.x, xv.y + yv.y, xv.z + yv.z, xv.w + yv.w};
  float s = v[0] + v[1] + v[2] + v[3];
  s = wave_sum(s);
  const float mean = s * (1.f / 256.f);
  float d[4] = {v[0] - mean, v[1] - mean, v[2] - mean, v[3] - mean};
  float sq = d[0] * d[0] + d[1] * d[1] + d[2] * d[2] + d[3] * d[3];
  sq = wave_sum(sq);
  const float inv = 1.f / sqrtf(sq * (1.f / 256.f) + 1e-5f);
  const float4 gv = *(const float4*)(g + lane * 4);
  const float4 bv = *(const float4*)(bta + lane * 4);
  float4 r;
  r.x = d[0] * inv * gv.x + bv.x; r.y = d[1] * inv * gv.y + bv.y;
  r.z = d[2] * inv * gv.z + bv.z; r.w = d[3] * inv * gv.w + bv.w;
  *(float4*)(out + base) = r;
}

// ---------------- gate logit -> mask ----------------------------------------
__global__ __launch_bounds__(256) void gate_mask(const float* __restrict__ t,
                                                 const float* __restrict__ Wg2,
                                                 const float* __restrict__ bg2,
                                                 int* __restrict__ mask) {
  const int row  = blockIdx.x * 4 + (threadIdx.x >> 6);
  const int lane = threadIdx.x & 63;
  const float4 tv = *(const float4*)(t + (size_t)row * D_ + lane * 4);
  const float4 wv = *(const float4*)(Wg2 + lane * 4);
  float s = tv.x * wv.x + tv.y * wv.y + tv.z * wv.z + tv.w * wv.w;
  s = wave_sum(s);
  if (lane == 0) mask[row] = (s + bg2[0]) > 0.f ? 1 : 0;
}

// ---------------- sequential prefix-scan over 16384 masks -------------------
__global__ __launch_bounds__(256) void scan_kernel(const int* __restrict__ mask,
                                                   int* __restrict__ slots,
                                                   int* __restrict__ countp) {
  __shared__ int ps[256];
  const int tid = threadIdx.x;
  const int base = tid * 64;
  int s = 0;
  for (int i = 0; i < 64; i++) s += mask[base + i];
  ps[tid] = s;
  __syncthreads();
  if (tid == 0) {
    int run = 0;
    for (int i = 0; i < 256; i++) { const int t = ps[i]; ps[i] = run; run += t; }
    countp[0] = run < M_ ? run : M_;
  }
  __syncthreads();
  int run = ps[tid];
  for (int i = 0; i < 64; i++) {
    const int r = base + i;
    const int mk = mask[r];
    slots[r] = (mk && run < M_) ? run : -1;
    run += mk;
  }
}

// ---------------- scatter selected rows into memory -------------------------
__global__ __launch_bounds__(256) void scatter_kernel(const float* __restrict__ h,
                                                      const int* __restrict__ slots,
                                                      float* __restrict__ mem) {
  const int row  = blockIdx.x * 4 + (threadIdx.x >> 6);
  const int lane = threadIdx.x & 63;
  const int sl = slots[row];
  if (sl >= 0)
    *(float4*)(mem + (size_t)sl * D_ + lane * 4) =
        *(const float4*)(h + (size_t)row * D_ + lane * 4);
}

// ---------------- query norms (one wave per batch row) ----------------------
__global__ __launch_bounds__(256) void qnorm_kernel(const float* __restrict__ h,
                                                    float* __restrict__ qden) {
  const int b    = blockIdx.x * 4 + (threadIdx.x >> 6);
  const int lane = threadIdx.x & 63;
  const float4 c = *(const float4*)(h + (size_t)b * S_ * D_ + lane * 4);
  float sq = c.x * c.x + c.y * c.y + c.z * c.z + c.w * c.w;
  sq = wave_sum(sq);
  if (lane == 0) qden[b] = sqrtf(sq) + 1e-8f;
}

// ------- sims[b][r] for all 32 b: one wave per memory row r -----------------
__global__ __launch_bounds__(256) void sims_kernel(const float* __restrict__ h,
                                                   const float* __restrict__ mem,
                                                   const float* __restrict__ qden,
                                                   const int* __restrict__ countp,
                                                   float* __restrict__ sims) {
  __shared__ float cls[B_ * D_];
  __shared__ float qd[B_];
  const int tid = threadIdx.x;
  const int lane = tid & 63, wid = tid >> 6;
  for (int i = tid; i < B_ * D_ / 4; i += 256) {
    const int flat = i * 4;
    const int b = flat >> 8, d = flat & 255;
    *(float4*)&cls[flat] = *(const float4*)(h + (size_t)b * S_ * D_ + d);
  }
  if (tid < B_) qd[tid] = qden[tid];
  __syncthreads();
  const int count = countp[0];
  const int r = blockIdx.x * 4 + wid;
  const float4 m4 = *(const float4*)(mem + (size_t)r * D_ + lane * 4);
  float sq = m4.x * m4.x + m4.y * m4.y + m4.z * m4.z + m4.w * m4.w;
  sq = wave_sum(sq);
  const float rn = sqrtf(sq) + 1e-8f;
  if (r < count) {
    for (int b = 0; b < B_; b++) {
      const float4 c4 = *(const float4*)&cls[b * D_ + lane * 4];
      float dt = m4.x * c4.x + m4.y * c4.y + m4.z * c4.z + m4.w * c4.w;
      dt = wave_sum(dt);
      if (lane == 0) sims[b * M_ + r] = dt / (qd[b] * rn);
    }
  } else if (lane == 0) {
    for (int b = 0; b < B_; b++) sims[b * M_ + r] = -1e9f;
  }
}

// ---------------- per-batch: top-4, softmax mix, classifier -----------------
__global__ __launch_bounds__(256) void topk_mix(const float* __restrict__ h,
                                                const float* __restrict__ mem,
                                                const float* __restrict__ simsg,
                                                const int* __restrict__ countp,
                                                const float* __restrict__ Wc,
                                                const float* __restrict__ bc,
                                                float* __restrict__ out) {
  __shared__ float sims[M_];
  __shared__ float cls[D_];
  __shared__ float rv[256];
  __shared__ int   ri[256];
  __shared__ float aug[D_];
  __shared__ float tv[4];
  __shared__ int   tix[4];

  const int b = blockIdx.x, tid = threadIdx.x;
  const int lane = tid & 63, wid = tid >> 6;
  const int count = countp[0];

  for (int i = tid; i < M_; i += 256) sims[i] = simsg[b * M_ + i];
  cls[tid] = h[(size_t)b * S_ * D_ + tid];
  __syncthreads();

  for (int k = 0; k < 4; k++) {
    float bv = -INFINITY; int bi = 1 << 30;
    for (int r = tid; r < M_; r += 256) {
      const float v = sims[r];
      if (v > bv || (v == bv && r < bi)) { bv = v; bi = r; }
    }
    rv[tid] = bv; ri[tid] = bi;
    __syncthreads();
    if (tid == 0) {
      float bb = rv[0]; int bbi = ri[0];
      for (int i = 1; i < 256; i++)
        if (rv[i] > bb || (rv[i] == bb && ri[i] < bbi)) { bb = rv[i]; bbi = ri[i]; }
      tv[k] = bb; tix[k] = bbi; sims[bbi] = -INFINITY;
    }
    __syncthreads();
  }

  float w[4];
  {
    const float mx = tv[0];
    float ws = 0.f;
#pragma unroll
    for (int k = 0; k < 4; k++) { w[k] = expf(tv[k] - mx); ws += w[k]; }
    const float inv = 1.f / ws;
#pragma unroll
    for (int k = 0; k < 4; k++) w[k] *= inv;
  }

  {
    float mv = 0.f;
    if (count > 0) {
#pragma unroll
      for (int k = 0; k < 4; k++) mv = fmaf(w[k], mem[(size_t)tix[k] * D_ + tid], mv);
    }
    aug[tid] = cls[tid] + mv;
  }
  __syncthreads();

  const float4 a4 = *(const float4*)&aug[lane * 4];
  for (int c = wid; c < NC_; c += 4) {
    const float4 wc = *(const float4*)(Wc + (size_t)c * D_ + lane * 4);
    float dt = a4.x * wc.x + a4.y * wc.y + a4.z * wc.z + a4.w * wc.w;
    dt = wave_sum(dt);
    if (lane == 0) out[b * NC_ + c] = dt + bc[c];
  }
}

// ---------------- launcher ---------------------------------------------------
extern "C" void kernel_launch(void* const* d_in, const int* in_sizes, int n_in,
                              void* d_out, int out_size, void* d_ws, size_t ws_size,
                              hipStream_t stream) {
  const int*   ids  = (const int*)d_in[0];
  const float* tok  = (const float*)d_in[1];
  const float* pos  = (const float*)d_in[2];
  const float* Wqkv = (const float*)d_in[3];
  const float* bqkv = (const float*)d_in[4];
  const float* Wo   = (const float*)d_in[5];
  const float* bo   = (const float*)d_in[6];
  const float* ln1g = (const float*)d_in[7];
  const float* ln1b = (const float*)d_in[8];
  const float* W1   = (const float*)d_in[9];
  const float* b1   = (const float*)d_in[10];
  const float* W2   = (const float*)d_in[11];
  const float* b2   = (const float*)d_in[12];
  const float* ln2g = (const float*)d_in[13];
  const float* ln2b = (const float*)d_in[14];
  const float* Wg1  = (const float*)d_in[15];
  const float* bg1  = (const float*)d_in[16];
  const float* Wg2  = (const float*)d_in[17];
  const float* bg2  = (const float*)d_in[18];
  const float* Wc   = (const float*)d_in[19];
  const float* bc   = (const float*)d_in[20];
  float* out = (float*)d_out;

  float* xA   = (float*)d_ws;
  float* xB   = xA  + (size_t)ROWS * D_;
  float* ob   = xB  + (size_t)ROWS * D_;
  float* pb   = ob  + (size_t)ROWS * D_;
  float* big  = pb  + (size_t)ROWS * D_;
  float* mem  = big + (size_t)ROWS * FF_;
  float* qden = mem + (size_t)M_ * D_;
  float* sims = qden + 64;
  int*   mask = (int*)(sims + (size_t)B_ * M_);
  int*   slots = mask + ROWS;
  int*   cnt   = slots + ROWS;

  emb_kernel<<<ROWS / 4, 256, 0, stream>>>(ids, tok, pos, xA);

  for (int l = 0; l < L_; l++) {
    gemm_mfma<128, 0><<<dim3(768 / 128, ROWS / 128), 512, 0, stream>>>(
        xA, Wqkv + (size_t)l * 768 * 256, bqkv + l * 768, big, ROWS, 768, 256);
    attn_mfma<<<B_ * H_, 512, 0, stream>>>(big, ob);
    gemm_mfma<64, 0><<<dim3(256 / 128, ROWS / 64), 512, 0, stream>>>(
        ob, Wo + (size_t)l * 256 * 256, bo + l * 256, pb, ROWS, 256, 256);
    add_ln<<<ROWS / 4, 256, 0, stream>>>(xA, pb, ln1g + l * 256, ln1b + l * 256, xB);
    gemm_mfma<128, 1><<<dim3(1024 / 128, ROWS / 128), 512, 0, stream>>>(
        xB, W1 + (size_t)l * 1024 * 256, b1 + l * 1024, big, ROWS, 1024, 256);
    gemm_mfma<64, 0><<<dim3(256 / 128, ROWS / 64), 512, 0, stream>>>(
        big, W2 + (size_t)l * 256 * 1024, b2 + l * 256, pb, ROWS, 256, 1024);
    add_ln<<<ROWS / 4, 256, 0, stream>>>(xB, pb, ln2g + l * 256, ln2b + l * 256, xA);
  }

  // gate MLP: t = relu(h @ Wg1^T + bg1)  -> mask
  gemm_mfma<64, 1><<<dim3(256 / 128, ROWS / 64), 512, 0, stream>>>(
      xA, Wg1, bg1, ob, ROWS, 256, 256);
  gate_mask<<<ROWS / 4, 256, 0, stream>>>(ob, Wg2, bg2, mask);
  scan_kernel<<<1, 256, 0, stream>>>(mask, slots, cnt);
  (void)hipMemsetAsync(mem, 0, (size_t)M_ * D_ * sizeof(float), stream);
  scatter_kernel<<<ROWS / 4, 256, 0, stream>>>(xA, slots, mem);

  qnorm_kernel<<<B_ / 4, 256, 0, stream>>>(xA, qden);
  sims_kernel<<<M_ / 4, 256, 0, stream>>>(xA, mem, qden, cnt, sims);
  topk_mix<<<B_, 256, 0, stream>>>(xA, mem, sims, cnt, Wc, bc, out);
}

// Round 6
// 507.575 us; speedup vs baseline: 4.6597x; 1.1379x over previous
//
#include <hip/hip_runtime.h>
#include <math.h>

#define D_   256
#define H_   8
#define L_   2
#define FF_  1024
#define S_   512
#define B_   32
#define M_   4096
#define NC_  10
#define ROWS (B_*S_)   // 16384

typedef __attribute__((ext_vector_type(8))) short bf16x8;
typedef __attribute__((ext_vector_type(4))) float f32x4;

__device__ __forceinline__ float wave_sum(float v) {
#pragma unroll
  for (int off = 1; off < 64; off <<= 1) v += __shfl_xor(v, off, 64);
  return v;
}

__device__ __forceinline__ unsigned short bf16_rne(float x) {
  unsigned int b = __float_as_uint(x);
  return (unsigned short)((b + 0x7FFFu + ((b >> 16) & 1u)) >> 16);
}
__device__ __forceinline__ float bf16_f(unsigned short h) {
  return __uint_as_float(((unsigned int)h) << 16);
}
__device__ __forceinline__ unsigned int cvt_pk_bf16(float a, float b) {
  unsigned int r;
  asm volatile("v_cvt_pk_bf16_f32 %0, %1, %2" : "=v"(r) : "v"(a), "v"(b));
  return r;
}

// convert float4 -> hi/lo bf16 quads, store 8B each into padded LDS tiles
__device__ __forceinline__ void cvt_store(unsigned short* Hq, unsigned short* Lq,
                                          int off, float4 v) {
  float f[4] = {v.x, v.y, v.z, v.w};
  unsigned short h[4], l[4];
#pragma unroll
  for (int i = 0; i < 4; i++) {
    h[i] = bf16_rne(f[i]);
    l[i] = bf16_rne(f[i] - bf16_f(h[i]));
  }
  uint2 hp, lp;
  hp.x = (unsigned int)h[0] | ((unsigned int)h[1] << 16);
  hp.y = (unsigned int)h[2] | ((unsigned int)h[3] << 16);
  lp.x = (unsigned int)l[0] | ((unsigned int)l[1] << 16);
  lp.y = (unsigned int)l[2] | ((unsigned int)l[3] << 16);
  *(uint2*)&Hq[off] = hp;
  *(uint2*)&Lq[off] = lp;
}

// ---------------- embedding ----------------
__global__ __launch_bounds__(256) void emb_kernel(const int* __restrict__ ids,
                                                  const float* __restrict__ tok,
                                                  const float* __restrict__ pos,
                                                  float* __restrict__ x) {
  const int row  = blockIdx.x * 4 + (threadIdx.x >> 6);
  const int lane = threadIdx.x & 63;
  const int id = ids[row];
  const int s  = row & (S_ - 1);
  const float4 t = *(const float4*)(tok + (size_t)id * D_ + lane * 4);
  const float4 p = *(const float4*)(pos + (size_t)s  * D_ + lane * 4);
  float4 r; r.x = t.x + p.x; r.y = t.y + p.y; r.z = t.z + p.z; r.w = t.w + p.w;
  *(float4*)(x + (size_t)row * D_ + lane * 4) = r;
}

// ---- split-bf16 MFMA GEMM: C[M,N] = A[M,K]*W[N,K]^T + bias (+ReLU) --------
#define LPITCH 40
template<int BM, int RELU>
__global__ __launch_bounds__(512, 4) void gemm_mfma(const float* __restrict__ A,
                                                    const float* __restrict__ Bm,
                                                    const float* __restrict__ bias,
                                                    float* __restrict__ C,
                                                    int M, int N, int K) {
  constexpr int WGM = BM / 64;
  constexpr int WGN = 8 / WGM;
  constexpr int WN  = 128 / WGN;
  constexpr int FN  = WN / 16;
  __shared__ unsigned short Ah[BM * LPITCH];
  __shared__ unsigned short Al[BM * LPITCH];
  __shared__ unsigned short Bh[128 * LPITCH];
  __shared__ unsigned short Bl[128 * LPITCH];

  const int tid  = threadIdx.x;
  const int lane = tid & 63;
  const int wid  = tid >> 6;
  const int wm = wid / WGN, wn = wid % WGN;
  const int m0 = blockIdx.y * BM, n0 = blockIdx.x * 128;
  const int lrow  = lane & 15;
  const int khalf = (lane >> 4) * 8;

  f32x4 acc[4][FN];
#pragma unroll
  for (int i = 0; i < 4; i++)
#pragma unroll
    for (int j = 0; j < FN; j++) acc[i][j] = (f32x4){0.f, 0.f, 0.f, 0.f};

  const float* Abase = A + (size_t)m0 * K;
  const float* Bbase = Bm + (size_t)n0 * K;

  for (int k0 = 0; k0 < K; k0 += 32) {
    __syncthreads();
#pragma unroll
    for (int j = 0; j < BM / 64; j++) {
      const int idx = tid + j * 512;
      const int row = idx >> 3, kq = (idx & 7) << 2;
      const float4 v = *(const float4*)(Abase + (size_t)row * K + k0 + kq);
      cvt_store(Ah, Al, row * LPITCH + kq, v);
    }
#pragma unroll
    for (int j = 0; j < 2; j++) {
      const int idx = tid + j * 512;
      const int row = idx >> 3, kq = (idx & 7) << 2;
      const float4 v = *(const float4*)(Bbase + (size_t)row * K + k0 + kq);
      cvt_store(Bh, Bl, row * LPITCH + kq, v);
    }
    __syncthreads();

    bf16x8 ah[4], al[4], bh[FN], bl[FN];
#pragma unroll
    for (int fm = 0; fm < 4; fm++) {
      const int r = (wm * 64 + fm * 16 + lrow) * LPITCH + khalf;
      ah[fm] = *(const bf16x8*)&Ah[r];
      al[fm] = *(const bf16x8*)&Al[r];
    }
#pragma unroll
    for (int fn = 0; fn < FN; fn++) {
      const int r = (wn * WN + fn * 16 + lrow) * LPITCH + khalf;
      bh[fn] = *(const bf16x8*)&Bh[r];
      bl[fn] = *(const bf16x8*)&Bl[r];
    }
#pragma unroll
    for (int fm = 0; fm < 4; fm++)
#pragma unroll
      for (int fn = 0; fn < FN; fn++) {
        acc[fm][fn] = __builtin_amdgcn_mfma_f32_16x16x32_bf16(ah[fm], bh[fn], acc[fm][fn], 0, 0, 0);
        acc[fm][fn] = __builtin_amdgcn_mfma_f32_16x16x32_bf16(ah[fm], bl[fn], acc[fm][fn], 0, 0, 0);
        acc[fm][fn] = __builtin_amdgcn_mfma_f32_16x16x32_bf16(al[fm], bh[fn], acc[fm][fn], 0, 0, 0);
      }
  }

#pragma unroll
  for (int fm = 0; fm < 4; fm++)
#pragma unroll
    for (int fn = 0; fn < FN; fn++) {
      const int mrow = m0 + wm * 64 + fm * 16 + (lane >> 4) * 4;
      const int ncol = n0 + wn * WN + fn * 16 + (lane & 15);
      const float bi = bias[ncol];
#pragma unroll
      for (int r = 0; r < 4; r++) {
        float v = acc[fm][fn][r] + bi;
        if (RELU) v = fmaxf(v, 0.f);
        C[(size_t)(mrow + r) * N + ncol] = v;
      }
    }
}

// ---------------- MFMA attention -------------------------------------------
#define KPITCH 40   // u16 per K row   (80B, 16B aligned, 2-way-free b128 reads)
#define VPITCH 520  // u16 per Vt row  (1040B, 16B aligned, 2-way-free)
__global__ __launch_bounds__(512, 2) void attn_mfma(const float* __restrict__ qkv,
                                                    float* __restrict__ o) {
  __shared__ unsigned short Kh[512 * KPITCH];
  __shared__ unsigned short Kl[512 * KPITCH];
  __shared__ unsigned short Vth[32 * VPITCH];
  __shared__ unsigned short Vtl[32 * VPITCH];

  const int bh = blockIdx.x;
  const int b = bh >> 3, h = bh & 7;
  const int tid = threadIdx.x;
  const int lane = tid & 63;
  const int wv = tid >> 6;
  const float* base = qkv + (size_t)b * (S_ * 768) + h * 32;

  // ---- stage: threads 0..255 -> V^T (2 rows each), 256..511 -> K (2 rows) --
  if (tid < 256) {
    float v0[32], v1[32];
    const float* p0 = base + (size_t)(2 * tid) * 768 + 512;
    const float* p1 = p0 + 768;
#pragma unroll
    for (int i = 0; i < 8; i++) {
      *(float4*)&v0[i * 4] = *(const float4*)(p0 + i * 4);
      *(float4*)&v1[i * 4] = *(const float4*)(p1 + i * 4);
    }
#pragma unroll
    for (int d = 0; d < 32; d++) {
      const unsigned short h0 = bf16_rne(v0[d]), h1 = bf16_rne(v1[d]);
      const unsigned short l0 = bf16_rne(v0[d] - bf16_f(h0));
      const unsigned short l1 = bf16_rne(v1[d] - bf16_f(h1));
      *(unsigned int*)&Vth[d * VPITCH + 2 * tid] = (unsigned int)h0 | ((unsigned int)h1 << 16);
      *(unsigned int*)&Vtl[d * VPITCH + 2 * tid] = (unsigned int)l0 | ((unsigned int)l1 << 16);
    }
  } else {
    const int t = tid - 256;
#pragma unroll
    for (int rr = 0; rr < 2; rr++) {
      const int k = 2 * t + rr;
      const float* p = base + (size_t)k * 768 + 256;
      float kv[32];
#pragma unroll
      for (int i = 0; i < 8; i++) *(float4*)&kv[i * 4] = *(const float4*)(p + i * 4);
#pragma unroll
      for (int d = 0; d < 32; d += 2) {
        const unsigned short h0 = bf16_rne(kv[d]), h1 = bf16_rne(kv[d + 1]);
        const unsigned short l0 = bf16_rne(kv[d] - bf16_f(h0));
        const unsigned short l1 = bf16_rne(kv[d + 1] - bf16_f(h1));
        *(unsigned int*)&Kh[k * KPITCH + d] = (unsigned int)h0 | ((unsigned int)h1 << 16);
        *(unsigned int*)&Kl[k * KPITCH + d] = (unsigned int)l0 | ((unsigned int)l1 << 16);
      }
    }
  }

  // ---- per-wave Q B-fragments (scale folded in), kept in registers --------
  const int q0 = wv * 64;
  bf16x8 qh[4], ql[4];
#pragma unroll
  for (int f = 0; f < 4; f++) {
    const float* qp = base + (size_t)(q0 + f * 16 + (lane & 15)) * 768 + ((lane >> 4) * 8);
    float qq[8];
    *(float4*)&qq[0] = *(const float4*)qp;
    *(float4*)&qq[4] = *(const float4*)(qp + 4);
    bf16x8 vh, vl;
#pragma unroll
    for (int j = 0; j < 8; j++) {
      const float sv = qq[j] * 0.17677669529663687f;
      const unsigned short hh = bf16_rne(sv);
      vh[j] = (short)hh;
      vl[j] = (short)bf16_rne(sv - bf16_f(hh));
    }
    qh[f] = vh; ql[f] = vl;
  }

  __syncthreads();

  f32x4 oacc[2][4];   // [d-frag][q-frag], O^T: row=d, col=q
#pragma unroll
  for (int i = 0; i < 2; i++)
#pragma unroll
    for (int j = 0; j < 4; j++) oacc[i][j] = (f32x4){0.f, 0.f, 0.f, 0.f};
  float lacc[4] = {0.f, 0.f, 0.f, 0.f};

  const int idx01 = (lane & 15) + ((lane & 16) << 1);  // +32 if bit4 set
  const int idx23 = idx01 + 16;
  const bool hiSel = (lane & 32) != 0;

  for (int kt = 0; kt < S_; kt += 32) {
    bf16x8 kah[2], kal[2];
#pragma unroll
    for (int u = 0; u < 2; u++) {
      const int off = (kt + u * 16 + (lane & 15)) * KPITCH + ((lane >> 4) * 8);
      kah[u] = *(const bf16x8*)&Kh[off];
      kal[u] = *(const bf16x8*)&Kl[off];
    }
    bf16x8 vah[2], val[2];
#pragma unroll
    for (int df = 0; df < 2; df++) {
      const int off = (df * 16 + (lane & 15)) * VPITCH + kt + ((lane >> 4) * 8);
      vah[df] = *(const bf16x8*)&Vth[off];
      val[df] = *(const bf16x8*)&Vtl[off];
    }
    f32x4 s[2][4];
#pragma unroll
    for (int u = 0; u < 2; u++)
#pragma unroll
      for (int f = 0; f < 4; f++) {
        f32x4 a = (f32x4){0.f, 0.f, 0.f, 0.f};
        a = __builtin_amdgcn_mfma_f32_16x16x32_bf16(kal[u], qh[f], a, 0, 0, 0);
        a = __builtin_amdgcn_mfma_f32_16x16x32_bf16(kah[u], ql[f], a, 0, 0, 0);
        a = __builtin_amdgcn_mfma_f32_16x16x32_bf16(kah[u], qh[f], a, 0, 0, 0);
        s[u][f] = a;
      }
    unsigned int ah[2][4][2], alw[2][4][2];
#pragma unroll
    for (int u = 0; u < 2; u++)
#pragma unroll
      for (int f = 0; f < 4; f++) {
        const float p0 = __expf(s[u][f][0]);
        const float p1 = __expf(s[u][f][1]);
        const float p2 = __expf(s[u][f][2]);
        const float p3 = __expf(s[u][f][3]);
        lacc[f] += (p0 + p1) + (p2 + p3);
        const unsigned int h01 = cvt_pk_bf16(p0, p1);
        const unsigned int h23 = cvt_pk_bf16(p2, p3);
        const float r0 = p0 - __uint_as_float(h01 << 16);
        const float r1 = p1 - __uint_as_float(h01 & 0xffff0000u);
        const float r2 = p2 - __uint_as_float(h23 << 16);
        const float r3 = p3 - __uint_as_float(h23 & 0xffff0000u);
        ah[u][f][0] = h01; ah[u][f][1] = h23;
        alw[u][f][0] = cvt_pk_bf16(r0, r1);
        alw[u][f][1] = cvt_pk_bf16(r2, r3);
      }
#pragma unroll
    for (int f = 0; f < 4; f++) {
      union { unsigned int w[4]; bf16x8 v; } ph, pl;
      {
        const unsigned int t0 = (unsigned int)__shfl((int)ah[0][f][0], idx01, 64);
        const unsigned int t1 = (unsigned int)__shfl((int)ah[1][f][0], idx01, 64);
        ph.w[0] = hiSel ? t1 : t0;
      }
      {
        const unsigned int t0 = (unsigned int)__shfl((int)ah[0][f][1], idx01, 64);
        const unsigned int t1 = (unsigned int)__shfl((int)ah[1][f][1], idx01, 64);
        ph.w[1] = hiSel ? t1 : t0;
      }
      {
        const unsigned int t0 = (unsigned int)__shfl((int)ah[0][f][0], idx23, 64);
        const unsigned int t1 = (unsigned int)__shfl((int)ah[1][f][0], idx23, 64);
        ph.w[2] = hiSel ? t1 : t0;
      }
      {
        const unsigned int t0 = (unsigned int)__shfl((int)ah[0][f][1], idx23, 64);
        const unsigned int t1 = (unsigned int)__shfl((int)ah[1][f][1], idx23, 64);
        ph.w[3] = hiSel ? t1 : t0;
      }
      {
        const unsigned int t0 = (unsigned int)__shfl((int)alw[0][f][0], idx01, 64);
        const unsigned int t1 = (unsigned int)__shfl((int)alw[1][f][0], idx01, 64);
        pl.w[0] = hiSel ? t1 : t0;
      }
      {
        const unsigned int t0 = (unsigned int)__shfl((int)alw[0][f][1], idx01, 64);
        const unsigned int t1 = (unsigned int)__shfl((int)alw[1][f][1], idx01, 64);
        pl.w[1] = hiSel ? t1 : t0;
      }
      {
        const unsigned int t0 = (unsigned int)__shfl((int)alw[0][f][0], idx23, 64);
        const unsigned int t1 = (unsigned int)__shfl((int)alw[1][f][0], idx23, 64);
        pl.w[2] = hiSel ? t1 : t0;
      }
      {
        const unsigned int t0 = (unsigned int)__shfl((int)alw[0][f][1], idx23, 64);
        const unsigned int t1 = (unsigned int)__shfl((int)alw[1][f][1], idx23, 64);
        pl.w[3] = hiSel ? t1 : t0;
      }
#pragma unroll
      for (int df = 0; df < 2; df++) {
        oacc[df][f] = __builtin_amdgcn_mfma_f32_16x16x32_bf16(val[df], ph.v, oacc[df][f], 0, 0, 0);
        oacc[df][f] = __builtin_amdgcn_mfma_f32_16x16x32_bf16(vah[df], pl.v, oacc[df][f], 0, 0, 0);
        oacc[df][f] = __builtin_amdgcn_mfma_f32_16x16x32_bf16(vah[df], ph.v, oacc[df][f], 0, 0, 0);
      }
    }
  }

#pragma unroll
  for (int f = 0; f < 4; f++) {
    lacc[f] += __shfl_xor(lacc[f], 16, 64);
    lacc[f] += __shfl_xor(lacc[f], 32, 64);
  }
#pragma unroll
  for (int f = 0; f < 4; f++) {
    const float inv = 1.f / lacc[f];
    const int q = q0 + f * 16 + (lane & 15);
    float* op = o + (size_t)(b * S_ + q) * D_ + h * 32;
#pragma unroll
    for (int df = 0; df < 2; df++) {
      const int dbase = df * 16 + (lane >> 4) * 4;
#pragma unroll
      for (int r = 0; r < 4; r++)
        op[dbase + r] = oacc[df][f][r] * inv;
    }
  }
}

// ---------------- fused residual + layernorm (one wave per row) -------------
__global__ __launch_bounds__(256) void add_ln(const float* __restrict__ x,
                                              const float* __restrict__ y,
                                              const float* __restrict__ g,
                                              const float* __restrict__ bta,
                                              float* __restrict__ out) {
  const int row  = blockIdx.x * 4 + (threadIdx.x >> 6);
  const int lane = threadIdx.x & 63;
  const size_t base = (size_t)row * D_ + lane * 4;
  const float4 xv = *(const float4*)(x + base);
  const float4 yv = *(const float4*)(y + base);
  float v[4] = {xv.x + yv.x, xv.y + yv.y, xv.z + yv.z, xv.w + yv.w};
  float s = v[0] + v[1] + v[2] + v[3];
  s = wave_sum(s);
  const float mean = s * (1.f / 256.f);
  float d[4] = {v[0] - mean, v[1] - mean, v[2] - mean, v[3] - mean};
  float sq = d[0] * d[0] + d[1] * d[1] + d[2] * d[2] + d[3] * d[3];
  sq = wave_sum(sq);
  const float inv = 1.f / sqrtf(sq * (1.f / 256.f) + 1e-5f);
  const float4 gv = *(const float4*)(g + lane * 4);
  const float4 bv = *(const float4*)(bta + lane * 4);
  float4 r;
  r.x = d[0] * inv * gv.x + bv.x; r.y = d[1] * inv * gv.y + bv.y;
  r.z = d[2] * inv * gv.z + bv.z; r.w = d[3] * inv * gv.w + bv.w;
  *(float4*)(out + base) = r;
}

// ---------------- gate logit -> mask ----------------------------------------
__global__ __launch_bounds__(256) void gate_mask(const float* __restrict__ t,
                                                 const float* __restrict__ Wg2,
                                                 const float* __restrict__ bg2,
                                                 int* __restrict__ mask) {
  const int row  = blockIdx.x * 4 + (threadIdx.x >> 6);
  const int lane = threadIdx.x & 63;
  const float4 tv = *(const float4*)(t + (size_t)row * D_ + lane * 4);
  const float4 wv = *(const float4*)(Wg2 + lane * 4);
  float s = tv.x * wv.x + tv.y * wv.y + tv.z * wv.z + tv.w * wv.w;
  s = wave_sum(s);
  if (lane == 0) mask[row] = (s + bg2[0]) > 0.f ? 1 : 0;
}

// -------- parallel prefix-scan over 16384 masks (sequential semantics) ------
__global__ __launch_bounds__(256) void scan_kernel(const int* __restrict__ mask,
                                                   int* __restrict__ slots,
                                                   int* __restrict__ countp) {
  __shared__ int wtot[4];
  const int tid = threadIdx.x;
  const int lane = tid & 63, wid = tid >> 6;
  const int base = tid * 64;
  int s = 0;
#pragma unroll 8
  for (int i = 0; i < 64; i++) s += mask[base + i];
  // wave-inclusive scan
  int inc = s;
#pragma unroll
  for (int off = 1; off < 64; off <<= 1) {
    const int t = __shfl_up(inc, off, 64);
    if (lane >= off) inc += t;
  }
  if (lane == 63) wtot[wid] = inc;
  __syncthreads();
  int woff = 0;
#pragma unroll
  for (int w = 0; w < 4; w++) woff += (w < wid) ? wtot[w] : 0;
  const int total = wtot[0] + wtot[1] + wtot[2] + wtot[3];
  if (tid == 0) countp[0] = total < M_ ? total : M_;
  int run = woff + inc - s;  // exclusive prefix for this thread's chunk
  for (int i = 0; i < 64; i++) {
    const int r = base + i;
    const int mk = mask[r];
    slots[r] = (mk && run < M_) ? run : -1;
    run += mk;
  }
}

// ---------------- scatter selected rows into memory -------------------------
__global__ __launch_bounds__(256) void scatter_kernel(const float* __restrict__ h,
                                                      const int* __restrict__ slots,
                                                      float* __restrict__ mem) {
  const int row  = blockIdx.x * 4 + (threadIdx.x >> 6);
  const int lane = threadIdx.x & 63;
  const int sl = slots[row];
  if (sl >= 0)
    *(float4*)(mem + (size_t)sl * D_ + lane * 4) =
        *(const float4*)(h + (size_t)row * D_ + lane * 4);
}

// ---------------- query norms (one wave per batch row) ----------------------
__global__ __launch_bounds__(256) void qnorm_kernel(const float* __restrict__ h,
                                                    float* __restrict__ qden) {
  const int b    = blockIdx.x * 4 + (threadIdx.x >> 6);
  const int lane = threadIdx.x & 63;
  const float4 c = *(const float4*)(h + (size_t)b * S_ * D_ + lane * 4);
  float sq = c.x * c.x + c.y * c.y + c.z * c.z + c.w * c.w;
  sq = wave_sum(sq);
  if (lane == 0) qden[b] = sqrtf(sq) + 1e-8f;
}

// ------- sims[b][r] for all 32 b: one wave per memory row r -----------------
__global__ __launch_bounds__(256) void sims_kernel(const float* __restrict__ h,
                                                   const float* __restrict__ mem,
                                                   const float* __restrict__ qden,
                                                   const int* __restrict__ countp,
                                                   float* __restrict__ sims) {
  __shared__ float cls[B_ * D_];
  __shared__ float qd[B_];
  const int tid = threadIdx.x;
  const int lane = tid & 63, wid = tid >> 6;
  for (int i = tid; i < B_ * D_ / 4; i += 256) {
    const int flat = i * 4;
    const int b = flat >> 8, d = flat & 255;
    *(float4*)&cls[flat] = *(const float4*)(h + (size_t)b * S_ * D_ + d);
  }
  if (tid < B_) qd[tid] = qden[tid];
  __syncthreads();
  const int count = countp[0];
  const int r = blockIdx.x * 4 + wid;
  const float4 m4 = *(const float4*)(mem + (size_t)r * D_ + lane * 4);
  float sq = m4.x * m4.x + m4.y * m4.y + m4.z * m4.z + m4.w * m4.w;
  sq = wave_sum(sq);
  const float rn = sqrtf(sq) + 1e-8f;
  if (r < count) {
    for (int b = 0; b < B_; b++) {
      const float4 c4 = *(const float4*)&cls[b * D_ + lane * 4];
      float dt = m4.x * c4.x + m4.y * c4.y + m4.z * c4.z + m4.w * c4.w;
      dt = wave_sum(dt);
      if (lane == 0) sims[b * M_ + r] = dt / (qd[b] * rn);
    }
  } else if (lane == 0) {
    for (int b = 0; b < B_; b++) sims[b * M_ + r] = -1e9f;
  }
}

// ---------------- per-batch: top-4 (wave-parallel argmax), mix, classifier --
__global__ __launch_bounds__(256) void topk_mix(const float* __restrict__ h,
                                                const float* __restrict__ mem,
                                                const float* __restrict__ simsg,
                                                const int* __restrict__ countp,
                                                const float* __restrict__ Wc,
                                                const float* __restrict__ bc,
                                                float* __restrict__ out) {
  __shared__ float sims[M_];
  __shared__ float cls[D_];
  __shared__ float wv4[4];
  __shared__ int   wi4[4];
  __shared__ float aug[D_];
  __shared__ float tv[4];
  __shared__ int   tix[4];

  const int b = blockIdx.x, tid = threadIdx.x;
  const int lane = tid & 63, wid = tid >> 6;
  const int count = countp[0];

  for (int i = tid; i < M_; i += 256) sims[i] = simsg[b * M_ + i];
  cls[tid] = h[(size_t)b * S_ * D_ + tid];
  __syncthreads();

  for (int k = 0; k < 4; k++) {
    float bv = -INFINITY; int bi = 1 << 30;
#pragma unroll
    for (int rr = 0; rr < M_ / 256; rr++) {
      const int r = tid + rr * 256;
      const float v = sims[r];
      if (v > bv || (v == bv && r < bi)) { bv = v; bi = r; }
    }
    // wave argmax butterfly (tie: lower index)
#pragma unroll
    for (int off = 1; off < 64; off <<= 1) {
      const float ov = __shfl_xor(bv, off, 64);
      const int   oi = __shfl_xor(bi, off, 64);
      if (ov > bv || (ov == bv && oi < bi)) { bv = ov; bi = oi; }
    }
    if (lane == 0) { wv4[wid] = bv; wi4[wid] = bi; }
    __syncthreads();
    if (tid == 0) {
      float bb = wv4[0]; int bbi = wi4[0];
#pragma unroll
      for (int i = 1; i < 4; i++)
        if (wv4[i] > bb || (wv4[i] == bb && wi4[i] < bbi)) { bb = wv4[i]; bbi = wi4[i]; }
      tv[k] = bb; tix[k] = bbi; sims[bbi] = -INFINITY;
    }
    __syncthreads();
  }

  float w[4];
  {
    const float mx = tv[0];
    float ws = 0.f;
#pragma unroll
    for (int k = 0; k < 4; k++) { w[k] = expf(tv[k] - mx); ws += w[k]; }
    const float inv = 1.f / ws;
#pragma unroll
    for (int k = 0; k < 4; k++) w[k] *= inv;
  }

  {
    float mv = 0.f;
    if (count > 0) {
#pragma unroll
      for (int k = 0; k < 4; k++) mv = fmaf(w[k], mem[(size_t)tix[k] * D_ + tid], mv);
    }
    aug[tid] = cls[tid] + mv;
  }
  __syncthreads();

  const float4 a4 = *(const float4*)&aug[lane * 4];
  for (int c = wid; c < NC_; c += 4) {
    const float4 wc = *(const float4*)(Wc + (size_t)c * D_ + lane * 4);
    float dt = a4.x * wc.x + a4.y * wc.y + a4.z * wc.z + a4.w * wc.w;
    dt = wave_sum(dt);
    if (lane == 0) out[b * NC_ + c] = dt + bc[c];
  }
}

// ---------------- launcher ---------------------------------------------------
extern "C" void kernel_launch(void* const* d_in, const int* in_sizes, int n_in,
                              void* d_out, int out_size, void* d_ws, size_t ws_size,
                              hipStream_t stream) {
  const int*   ids  = (const int*)d_in[0];
  const float* tok  = (const float*)d_in[1];
  const float* pos  = (const float*)d_in[2];
  const float* Wqkv = (const float*)d_in[3];
  const float* bqkv = (const float*)d_in[4];
  const float* Wo   = (const float*)d_in[5];
  const float* bo   = (const float*)d_in[6];
  const float* ln1g = (const float*)d_in[7];
  const float* ln1b = (const float*)d_in[8];
  const float* W1   = (const float*)d_in[9];
  const float* b1   = (const float*)d_in[10];
  const float* W2   = (const float*)d_in[11];
  const float* b2   = (const float*)d_in[12];
  const float* ln2g = (const float*)d_in[13];
  const float* ln2b = (const float*)d_in[14];
  const float* Wg1  = (const float*)d_in[15];
  const float* bg1  = (const float*)d_in[16];
  const float* Wg2  = (const float*)d_in[17];
  const float* bg2  = (const float*)d_in[18];
  const float* Wc   = (const float*)d_in[19];
  const float* bc   = (const float*)d_in[20];
  float* out = (float*)d_out;

  float* xA   = (float*)d_ws;
  float* xB   = xA  + (size_t)ROWS * D_;
  float* ob   = xB  + (size_t)ROWS * D_;
  float* pb   = ob  + (size_t)ROWS * D_;
  float* big  = pb  + (size_t)ROWS * D_;
  float* mem  = big + (size_t)ROWS * FF_;
  float* qden = mem + (size_t)M_ * D_;
  float* sims = qden + 64;
  int*   mask = (int*)(sims + (size_t)B_ * M_);
  int*   slots = mask + ROWS;
  int*   cnt   = slots + ROWS;

  emb_kernel<<<ROWS / 4, 256, 0, stream>>>(ids, tok, pos, xA);

  for (int l = 0; l < L_; l++) {
    gemm_mfma<128, 0><<<dim3(768 / 128, ROWS / 128), 512, 0, stream>>>(
        xA, Wqkv + (size_t)l * 768 * 256, bqkv + l * 768, big, ROWS, 768, 256);
    attn_mfma<<<B_ * H_, 512, 0, stream>>>(big, ob);
    gemm_mfma<64, 0><<<dim3(256 / 128, ROWS / 64), 512, 0, stream>>>(
        ob, Wo + (size_t)l * 256 * 256, bo + l * 256, pb, ROWS, 256, 256);
    add_ln<<<ROWS / 4, 256, 0, stream>>>(xA, pb, ln1g + l * 256, ln1b + l * 256, xB);
    gemm_mfma<128, 1><<<dim3(1024 / 128, ROWS / 128), 512, 0, stream>>>(
        xB, W1 + (size_t)l * 1024 * 256, b1 + l * 1024, big, ROWS, 1024, 256);
    gemm_mfma<64, 0><<<dim3(256 / 128, ROWS / 64), 512, 0, stream>>>(
        big, W2 + (size_t)l * 256 * 1024, b2 + l * 256, pb, ROWS, 256, 1024);
    add_ln<<<ROWS / 4, 256, 0, stream>>>(xB, pb, ln2g + l * 256, ln2b + l * 256, xA);
  }

  // gate MLP: t = relu(h @ Wg1^T + bg1)  -> mask
  gemm_mfma<64, 1><<<dim3(256 / 128, ROWS / 64), 512, 0, stream>>>(
      xA, Wg1, bg1, ob, ROWS, 256, 256);
  gate_mask<<<ROWS / 4, 256, 0, stream>>>(ob, Wg2, bg2, mask);
  scan_kernel<<<1, 256, 0, stream>>>(mask, slots, cnt);
  (void)hipMemsetAsync(mem, 0, (size_t)M_ * D_ * sizeof(float), stream);
  scatter_kernel<<<ROWS / 4, 256, 0, stream>>>(xA, slots, mem);

  qnorm_kernel<<<B_ / 4, 256, 0, stream>>>(xA, qden);
  sims_kernel<<<M_ / 4, 256, 0, stream>>>(xA, mem, qden, cnt, sims);
  topk_mix<<<B_, 256, 0, stream>>>(xA, mem, sims, cnt, Wc, bc, out);
}